// Round 2
// baseline (723.365 us; speedup 1.0000x reference)
//
#include <hip/hip_runtime.h>
#include <cstdint>
#include <cstddef>

#define LQ 1024
#define LK 4096
#define NBATCH 8
#define DM 256
#define NH 4

typedef __attribute__((ext_vector_type(8))) __bf16 bf16x8;
typedef __attribute__((ext_vector_type(4))) float f32x4;
typedef __attribute__((ext_vector_type(4))) unsigned int u32x4;
typedef __attribute__((ext_vector_type(4))) short s16x4;

__device__ __forceinline__ unsigned short f2bf(float f) {
  unsigned int u = __builtin_bit_cast(unsigned int, f);
  u += 0x7FFFu + ((u >> 16) & 1u);  // RNE
  return (unsigned short)(u >> 16);
}
__device__ __forceinline__ unsigned pack2(float a, float b) {
  return (unsigned)f2bf(a) | ((unsigned)f2bf(b) << 16);
}
__device__ __forceinline__ bf16x8 ld_bf8(const unsigned short* p) {
  u32x4 u = *reinterpret_cast<const u32x4*>(p);
  return __builtin_bit_cast(bf16x8, u);
}
__device__ __forceinline__ f32x4 zero4() {
  f32x4 v; v.x = 0.f; v.y = 0.f; v.z = 0.f; v.w = 0.f; return v;
}

// async global->LDS, 16B per lane; LDS dest = wave-uniform base + lane*16
#define ASYNC16(ldsp, gp)                                                      \
  __builtin_amdgcn_global_load_lds(                                            \
      (const __attribute__((address_space(1))) unsigned int*)(gp),             \
      (__attribute__((address_space(3))) unsigned int*)(ldsp), 16, 0, 0)

// ---------------------------------------------------------------------------
// prep (x8 vectorized): out[(b*L+l)*256+d] = bf16(a[(l*8+b)*256+d] (+badd))
// ---------------------------------------------------------------------------
__global__ void prep_add_kernel(const float* __restrict__ a,
                                const float* __restrict__ badd,
                                unsigned short* __restrict__ out,
                                int L, int n8) {
  int i = blockIdx.x * blockDim.x + threadIdx.x;
  if (i >= n8) return;
  int base = i * 8;
  int d = base & 255;
  int rest = base >> 8;
  int bb = rest & 7, l = rest >> 3;
  f32x4 x0 = *reinterpret_cast<const f32x4*>(a + base);
  f32x4 x1 = *reinterpret_cast<const f32x4*>(a + base + 4);
  if (badd) {
    f32x4 y0 = *reinterpret_cast<const f32x4*>(badd + base);
    f32x4 y1 = *reinterpret_cast<const f32x4*>(badd + base + 4);
    x0 += y0; x1 += y1;
  }
  u32x4 o;
  o.x = pack2(x0.x, x0.y); o.y = pack2(x0.z, x0.w);
  o.z = pack2(x1.x, x1.y); o.w = pack2(x1.z, x1.w);
  *reinterpret_cast<u32x4*>(out + (((size_t)bb * L + l) << 8) + d) = o;
}

__global__ void conv_bf16_kernel(const float* __restrict__ src,
                                 unsigned short* __restrict__ dst, int n8) {
  int i = blockIdx.x * blockDim.x + threadIdx.x;
  if (i >= n8) return;
  int base = i * 8;
  f32x4 x0 = *reinterpret_cast<const f32x4*>(src + base);
  f32x4 x1 = *reinterpret_cast<const f32x4*>(src + base + 4);
  u32x4 o;
  o.x = pack2(x0.x, x0.y); o.y = pack2(x0.z, x0.w);
  o.z = pack2(x1.x, x1.y); o.w = pack2(x1.z, x1.w);
  *reinterpret_cast<u32x4*>(dst + base) = o;
}

// ---------------------------------------------------------------------------
// NT GEMM (unchanged): global_load_lds(16B), XOR-swizzled LDS.
// ---------------------------------------------------------------------------
template <int OUT_MODE>
__global__ void __launch_bounds__(256)
gemm_nt_kernel(const unsigned short* __restrict__ A, int lda, long long sA,
               const unsigned short* __restrict__ B, int ldb, long long sB,
               void* __restrict__ Cv, int ldc, long long sC,
               int K, float alpha) {
  __shared__ __align__(16) unsigned short As[128 * 64];
  __shared__ __align__(16) unsigned short Bs[128 * 64];
  const int t = threadIdx.x;
  const int bm0 = blockIdx.y * 128;
  const int bn0 = blockIdx.x * 128;
  A += (size_t)blockIdx.z * sA + (size_t)bm0 * lda;
  B += (size_t)blockIdx.z * sB + (size_t)bn0 * ldb;
  const int lane = t & 63, w = t >> 6;
  const int wm = (w >> 1) * 64, wn = (w & 1) * 64;
  const int lr = lane & 15, quad = lane >> 4;
  const int srl = lane >> 3;
  const int sc = (lane & 7) ^ (srl & 7);

  f32x4 acc[4][4];
#pragma unroll
  for (int i = 0; i < 4; ++i)
#pragma unroll
    for (int j = 0; j < 4; ++j) acc[i][j] = zero4();

  for (int k0 = 0; k0 < K; k0 += 64) {
#pragma unroll
    for (int i = 0; i < 4; ++i) {
      int r0 = w * 32 + i * 8;
      ASYNC16(&As[r0 * 64], &A[(size_t)(r0 + srl) * lda + k0 + sc * 8]);
      ASYNC16(&Bs[r0 * 64], &B[(size_t)(r0 + srl) * ldb + k0 + sc * 8]);
    }
    __syncthreads();
#pragma unroll
    for (int ks = 0; ks < 2; ++ks) {
      bf16x8 af[4], bfv[4];
#pragma unroll
      for (int i = 0; i < 4; ++i) {
        int m = wm + i * 16 + lr;
        int pc = (ks * 4 + quad) ^ (lr & 7);
        af[i] = ld_bf8(&As[m * 64 + pc * 8]);
      }
#pragma unroll
      for (int j = 0; j < 4; ++j) {
        int n = wn + j * 16 + lr;
        int pc = (ks * 4 + quad) ^ (lr & 7);
        bfv[j] = ld_bf8(&Bs[n * 64 + pc * 8]);
      }
#pragma unroll
      for (int i = 0; i < 4; ++i)
#pragma unroll
        for (int j = 0; j < 4; ++j)
          acc[i][j] = __builtin_amdgcn_mfma_f32_16x16x32_bf16(af[i], bfv[j], acc[i][j], 0, 0, 0);
    }
    __syncthreads();
  }

  if (OUT_MODE == 0) {
    float* C = (float*)Cv + (size_t)blockIdx.z * sC;
#pragma unroll
    for (int i = 0; i < 4; ++i) {
      int m0 = bm0 + wm + i * 16 + quad * 4;
#pragma unroll
      for (int j = 0; j < 4; ++j) {
        int n = bn0 + wn + j * 16 + lr;
#pragma unroll
        for (int r = 0; r < 4; ++r)
          C[(size_t)(m0 + r) * ldc + n] = acc[i][j][r] * alpha;
      }
    }
  } else if (OUT_MODE == 1) {
    unsigned short* C = (unsigned short*)Cv + (size_t)blockIdx.z * sC;
#pragma unroll
    for (int i = 0; i < 4; ++i) {
      int m0 = bm0 + wm + i * 16 + quad * 4;
#pragma unroll
      for (int j = 0; j < 4; ++j) {
        int n = bn0 + wn + j * 16 + lr;
#pragma unroll
        for (int r = 0; r < 4; ++r)
          C[(size_t)(m0 + r) * ldc + n] = f2bf(acc[i][j][r] * alpha);
      }
    }
  } else {
    unsigned short* C = (unsigned short*)Cv;
#pragma unroll
    for (int i = 0; i < 4; ++i) {
      int m0 = bm0 + wm + i * 16 + quad * 4;
      int bb = m0 >> 12;
      int kp = m0 & 4095;
#pragma unroll
      for (int j = 0; j < 4; ++j) {
        int n = bn0 + wn + j * 16 + lr;
        s16x4 pk;
#pragma unroll
        for (int r = 0; r < 4; ++r) pk[r] = (short)f2bf(acc[i][j][r] * alpha);
        *reinterpret_cast<s16x4*>(&C[((size_t)(bb * 1024 + n)) * 4096 + kp]) = pk;
      }
    }
  }
}

// ---------------------------------------------------------------------------
// Flash attention v4: occupancy-oriented restructure.
// Previous version: wave=32q, ~256 regs/lane (Oacc 128 + qf 64) -> 2 waves/SIMD,
// LDS 64KB -> 2 blocks/CU; counters showed ~75% stall (MfmaUtil 29, VALUBusy 25,
// Occ 21.7) on the serial QK->exp->bpermute->PV chain.
// Now: wave=16q (Oacc 64, qf 32, ~150 regs -> 3 waves/SIMD), K double-buffered +
// V single-buffered (48KB -> 3 blocks/CU). 2 barriers/tile:
//   ISSUE K(t+1); QK(t); softmax; PV(t); barrier(beta, drains K(t+1));
//   ISSUE V(t+1); barrier(gamma, drains V(t+1))
// gamma exposes ~1 V-load latency/tile/block; absorbed by 3-block overlap.
// Block covers 64 q rows -> grid 1024 blocks, decoded so all 16 qt-blocks of a
// (b,h,ks) KV slab land on one XCD (slab 2MB fits 4MB L2).
// ---------------------------------------------------------------------------
__global__ void __launch_bounds__(256, 3)
attn_kernel(const unsigned short* __restrict__ Qg,
            const unsigned short* __restrict__ Kg,
            const unsigned short* __restrict__ VTg,
            unsigned short* __restrict__ Opart,
            float* __restrict__ lpart) {
  __shared__ __align__(16) unsigned short Kt[2][32 * 256];  // [kpos][d], chunk^(row&7)
  __shared__ __align__(16) unsigned short Vt[256 * 32];     // [e][kpos], chunk^((row>>1)&3)
  const int t = threadIdx.x;
  // XCD-grouping decode: lin%8 constant for all 16 qt-blocks of a slab
  const int lin = blockIdx.x;
  const int xcd = lin & 7;
  const int blk = lin >> 3;       // 0..127
  const int qt = blk & 15;        // 16 q-tiles of 64 rows
  const int shi = blk >> 4;       // 0..7
  const int s_id = xcd + 8 * shi; // 0..63 slab id
  const int ks = s_id & 1, h = (s_id >> 1) & 3, b = s_id >> 3;
  const int lane = t & 63, w = t >> 6;
  const int lr = lane & 15, quad = lane >> 4;

  // Q B-frags: qf[s]: q = qt*64 + w*16 + lr, d = s*32 + quad*8..+7
  const unsigned short* Qrow0 =
      Qg + ((size_t)(b * 1024 + qt * 64 + w * 16 + lr)) * 1024 + h * 256;
  bf16x8 qf[8];
#pragma unroll
  for (int s = 0; s < 8; ++s) qf[s] = ld_bf8(&Qrow0[s * 32 + quad * 8]);

  f32x4 Oacc[16];
#pragma unroll
  for (int m2 = 0; m2 < 16; ++m2) Oacc[m2] = zero4();
  float lsum_r = 0.f;

  const unsigned short* Kb =
      Kg + ((size_t)(b * 4096 + ks * 2048)) * 1024 + h * 256;
  const unsigned short* Vb =
      VTg + ((size_t)(b * 1024 + h * 256)) * 4096 + ks * 2048;

  // staging index precompute
  const int k_rsub = lane >> 5;                 // row within pair
  const int k_chunk = lane & 31;                // phys chunk (of 32)
  const int v_rsub = lane >> 2;                 // row within 16
  const int v_chunk = lane & 3;                 // phys chunk (of 4)

#define ISSUE_K(kt, bufsel)                                                    \
  {                                                                            \
    _Pragma("unroll") for (int i = 0; i < 4; ++i) {                            \
      int r0 = w * 8 + i * 2;                                                  \
      int krow = r0 + k_rsub;                                                  \
      int kc = k_chunk ^ (krow & 7);                                           \
      ASYNC16(&Kt[bufsel][r0 * 256], &Kb[(size_t)((kt) + krow) * 1024 + kc * 8]); \
    }                                                                          \
  }
#define ISSUE_V(kt)                                                            \
  {                                                                            \
    _Pragma("unroll") for (int i = 0; i < 4; ++i) {                            \
      int vr0 = (w * 4 + i) * 16;                                              \
      int ve = vr0 + v_rsub;                                                   \
      int vc = v_chunk ^ ((ve >> 1) & 3);                                      \
      ASYNC16(&Vt[vr0 * 32], &Vb[(size_t)ve * 4096 + (kt) + vc * 8]);          \
    }                                                                          \
  }

  ISSUE_K(0, 0)
  ISSUE_V(0)
  __syncthreads();

  const int bpermA = (((quad & 1) * 32) + lr) * 4;  // src lane qs0*16+lr, bytes
  const int bpermB = bpermA + 64;                   // qs0+1

  for (int kt = 0; kt < 2048; kt += 32) {
    const int pb = (kt >> 5) & 1;
    // prefetch next K tile (tail iteration reads junk, stays in workspace)
    ISSUE_K(kt + 32, pb ^ 1)

    const unsigned short* Ktp = Kt[pb];

    // S^T[kpos][q]: A = K (m=kpos, 2 m-tiles), B = Q regs (1 n-tile of 16 q)
    f32x4 S[2];
    S[0] = zero4(); S[1] = zero4();
    __builtin_amdgcn_s_setprio(1);
#pragma unroll
    for (int s = 0; s < 8; ++s) {
      int pc = ((s * 4 + quad) ^ (lr & 7)) * 8;
      bf16x8 kf0 = ld_bf8(&Ktp[lr * 256 + pc]);
      bf16x8 kf1 = ld_bf8(&Ktp[(16 + lr) * 256 + pc]);
      S[0] = __builtin_amdgcn_mfma_f32_16x16x32_bf16(kf0, qf[s], S[0], 0, 0, 0);
      S[1] = __builtin_amdgcn_mfma_f32_16x16x32_bf16(kf1, qf[s], S[1], 0, 0, 0);
    }
    __builtin_amdgcn_s_setprio(0);

    // exp + pack to bf16 pairs
    unsigned pk[2][2];
#pragma unroll
    for (int mt = 0; mt < 2; ++mt) {
      float p0 = __expf(S[mt][0]);
      float p1 = __expf(S[mt][1]);
      float p2 = __expf(S[mt][2]);
      float p3 = __expf(S[mt][3]);
      lsum_r += (p0 + p1) + (p2 + p3);
      pk[mt][0] = pack2(p0, p1);
      pk[mt][1] = pack2(p2, p3);
    }

    // P^T C-layout -> B-operand: dest lane (lr,quad) elem j needs
    // kpos=quad*8+j, q=lr => src tile mt=quad>>1, src quad (quad&1)*2+(j>>2),
    // reg j&3.  ds_bpermute both tiles + select.
    u32x4 bfw;
#pragma unroll
    for (int w2 = 0; w2 < 2; ++w2) {
      int f0 = __builtin_amdgcn_ds_bpermute(bpermA, (int)pk[0][w2]);
      int f1 = __builtin_amdgcn_ds_bpermute(bpermA, (int)pk[1][w2]);
      bfw[w2] = (unsigned)(quad < 2 ? f0 : f1);
      int g0 = __builtin_amdgcn_ds_bpermute(bpermB, (int)pk[0][w2]);
      int g1 = __builtin_amdgcn_ds_bpermute(bpermB, (int)pk[1][w2]);
      bfw[2 + w2] = (unsigned)(quad < 2 ? g0 : g1);
    }
    bf16x8 pfrag = __builtin_bit_cast(bf16x8, bfw);

    // PV: O^T[e][q] += V^T * P^T ; A = V^T (m=e), k = 32 kpos, 1 k-step
    __builtin_amdgcn_s_setprio(1);
#pragma unroll
    for (int m2 = 0; m2 < 16; ++m2) {
      bf16x8 vf = ld_bf8(&Vt[(m2 * 16 + lr) * 32 + (quad ^ ((lr >> 1) & 3)) * 8]);
      Oacc[m2] = __builtin_amdgcn_mfma_f32_16x16x32_bf16(vf, pfrag, Oacc[m2], 0, 0, 0);
    }
    __builtin_amdgcn_s_setprio(0);

    __syncthreads();  // beta: all waves done reading Vt; drains K(t+1)
    ISSUE_V(kt + 32)  // tail iteration reads junk, stays in workspace
    __syncthreads();  // gamma: drains V(t+1)
  }
#undef ISSUE_K
#undef ISSUE_V

  const int pidx = b * 4 + h;
  // lsum: reduce across quads (q lives in lr; partials spread over quad)
  {
    float l = lsum_r;
    l += __shfl_xor(l, 16, 64);
    l += __shfl_xor(l, 32, 64);
    if (quad == 0)
      lpart[((size_t)(ks * 32 + pidx)) * 1024 + qt * 64 + w * 16 + lr] = l;
  }

  // Opart[ks][p][e][q] bf16 (same format combine expects)
  const size_t base = ((size_t)(ks * 32 + pidx)) * 256 * 1024;
  const int qg0 = qt * 64 + w * 16 + lr;
#pragma unroll
  for (int m2 = 0; m2 < 16; ++m2) {
#pragma unroll
    for (int r = 0; r < 4; ++r) {
      int e = m2 * 16 + quad * 4 + r;
      Opart[base + (size_t)e * 1024 + qg0] = f2bf(Oacc[m2][r]);
    }
  }
}

// ---------------------------------------------------------------------------
// combine: O = (Oa+Ob)/(la+lb), transpose [e][q] -> row-major [q][h*256+e]
// ---------------------------------------------------------------------------
__global__ void __launch_bounds__(256)
combine_kernel(const unsigned short* __restrict__ Opart,
               const float* __restrict__ lpart,
               unsigned short* __restrict__ Oall) {
  __shared__ float rl[64];
  __shared__ __align__(16) unsigned short T[64][264];
  const int t = threadIdx.x;
  const int qt = blockIdx.x, h = blockIdx.y, b = blockIdx.z;
  const int p = b * 4 + h;
  const int q0 = qt * 64;
  const size_t slabO = (size_t)32 * 256 * 1024;
  const size_t slabL = (size_t)32 * 1024;
  if (t < 64) {
    float la = lpart[(size_t)p * 1024 + q0 + t];
    float lb = lpart[slabL + (size_t)p * 1024 + q0 + t];
    rl[t] = 1.f / (la + lb);
  }
  __syncthreads();
  const int er = t >> 3, q8 = t & 7;
#pragma unroll
  for (int ei = 0; ei < 8; ++ei) {
    int e = ei * 32 + er;
    size_t idx = ((size_t)p * 256 + e) * 1024 + q0 + q8 * 8;
    u32x4 ua = *reinterpret_cast<const u32x4*>(&Opart[idx]);
    u32x4 ub = *reinterpret_cast<const u32x4*>(&Opart[slabO + idx]);
#pragma unroll
    for (int wd = 0; wd < 4; ++wd) {
      unsigned a = ((const unsigned*)&ua)[wd], bb2 = ((const unsigned*)&ub)[wd];
      float a0 = __builtin_bit_cast(float, a << 16);
      float a1 = __builtin_bit_cast(float, a & 0xFFFF0000u);
      float b0 = __builtin_bit_cast(float, bb2 << 16);
      float b1 = __builtin_bit_cast(float, bb2 & 0xFFFF0000u);
      int qA = q8 * 8 + wd * 2;
      T[qA + 0][e] = f2bf((a0 + b0) * rl[qA + 0]);
      T[qA + 1][e] = f2bf((a1 + b1) * rl[qA + 1]);
    }
  }
  __syncthreads();
  const int ql = t >> 2, ec = t & 3;
  const size_t orow = ((size_t)(b * 1024 + q0 + ql)) * 1024 + h * 256;
#pragma unroll
  for (int i = 0; i < 8; ++i) {
    int ch = ec * 8 + i;
    *reinterpret_cast<u32x4*>(&Oall[orow + ch * 8]) =
        *reinterpret_cast<const u32x4*>(&T[ql][ch * 8]);
  }
}

// ---------------------------------------------------------------------------
// residual + LayerNorm: one wave per row of 256
// ---------------------------------------------------------------------------
__global__ void __launch_bounds__(256)
fc_ln_kernel(const float* __restrict__ fc, const float* __restrict__ tgt,
             const float* __restrict__ g, const float* __restrict__ bb,
             float* __restrict__ y) {
  int row = blockIdx.x * 4 + (threadIdx.x >> 6);
  int lane = threadIdx.x & 63;
  int b = row >> 10, q = row & 1023;
  const float* fr = fc + (size_t)row * 256;
  const float* tr = tgt + ((size_t)(q * 8 + b)) * 256;
  float x[4];
  float s = 0.f, ss = 0.f;
#pragma unroll
  for (int e = 0; e < 4; ++e) {
    x[e] = fr[lane + e * 64] + tr[lane + e * 64];
    s += x[e];
    ss += x[e] * x[e];
  }
#pragma unroll
  for (int d = 1; d < 64; d <<= 1) {
    s += __shfl_xor(s, d, 64);
    ss += __shfl_xor(ss, d, 64);
  }
  float mu = s * (1.f / 256.f);
  float var = ss * (1.f / 256.f) - mu * mu;
  float rs = rsqrtf(var + 1e-5f);
  float* yr = y + ((size_t)(q * 8 + b)) * 256;
#pragma unroll
  for (int e = 0; e < 4; ++e)
    yr[lane + e * 64] = (x[e] - mu) * rs * g[lane + e * 64] + bb[lane + e * 64];
}

// ---------------------------------------------------------------------------
extern "C" void kernel_launch(void* const* d_in, const int* in_sizes, int n_in,
                              void* d_out, int out_size, void* d_ws, size_t ws_size,
                              hipStream_t stream) {
  (void)in_sizes; (void)n_in; (void)out_size; (void)ws_size;
  const float* tgt    = (const float*)d_in[0];
  const float* memory = (const float*)d_in[1];
  const float* pos    = (const float*)d_in[2];
  const float* qpos   = (const float*)d_in[3];
  const float* Wq     = (const float*)d_in[4];
  const float* Wk     = (const float*)d_in[5];
  const float* Wv     = (const float*)d_in[6];
  const float* Wfc    = (const float*)d_in[7];
  const float* lng    = (const float*)d_in[8];
  const float* lnb    = (const float*)d_in[9];
  float* out = (float*)d_out;

  char* ws = (char*)d_ws;
  const size_t MB = 1024 * 1024;
  unsigned short* Wq_b  = (unsigned short*)(ws + 0);
  unsigned short* Wk_b  = (unsigned short*)(ws + 512 * 1024);
  unsigned short* Wv_b  = (unsigned short*)(ws + 1 * MB);
  unsigned short* Wfc_b = (unsigned short*)(ws + 1 * MB + 512 * 1024);
  unsigned short* A_q   = (unsigned short*)(ws + 2 * MB);
  unsigned short* A_k   = (unsigned short*)(ws + 6 * MB);
  unsigned short* A_v   = (unsigned short*)(ws + 22 * MB);
  unsigned short* Qall  = (unsigned short*)(ws + 38 * MB);
  unsigned short* Kall  = (unsigned short*)(ws + 54 * MB);
  unsigned short* VTb   = (unsigned short*)(ws + 118 * MB);
  unsigned short* Opart = (unsigned short*)(ws + 2 * MB);
  float* lpart          = (float*)(ws + 36 * MB);
  unsigned short* Oall  = (unsigned short*)(ws + 118 * MB);
  float* fcout          = (float*)(ws + 140 * MB);
  float* y = out;
  float* attn_mean = out + (size_t)LQ * NBATCH * DM;

  int n_q = LQ * NBATCH * DM;
  int n_k = LK * NBATCH * DM;
  prep_add_kernel<<<(n_q / 8 + 255) / 256, 256, 0, stream>>>(tgt, qpos, A_q, LQ, n_q / 8);
  prep_add_kernel<<<(n_k / 8 + 255) / 256, 256, 0, stream>>>(memory, pos, A_k, LK, n_k / 8);
  prep_add_kernel<<<(n_k / 8 + 255) / 256, 256, 0, stream>>>(memory, nullptr, A_v, LK, n_k / 8);
  int n_w8 = 1024 * 256 / 8;
  conv_bf16_kernel<<<(n_w8 + 255) / 256, 256, 0, stream>>>(Wq, Wq_b, n_w8);
  conv_bf16_kernel<<<(n_w8 + 255) / 256, 256, 0, stream>>>(Wk, Wk_b, n_w8);
  conv_bf16_kernel<<<(n_w8 + 255) / 256, 256, 0, stream>>>(Wv, Wv_b, n_w8);
  conv_bf16_kernel<<<(n_w8 + 255) / 256, 256, 0, stream>>>(Wfc, Wfc_b, n_w8);

  gemm_nt_kernel<1><<<dim3(8, 64, 1), 256, 0, stream>>>(
      A_q, 256, 0LL, Wq_b, 256, 0LL, (void*)Qall, 1024, 0LL, 256, 0.0625f);
  gemm_nt_kernel<1><<<dim3(8, 256, 1), 256, 0, stream>>>(
      A_k, 256, 0LL, Wk_b, 256, 0LL, (void*)Kall, 1024, 0LL, 256, 1.0f);
  gemm_nt_kernel<2><<<dim3(8, 256, 1), 256, 0, stream>>>(
      A_v, 256, 0LL, Wv_b, 256, 0LL, (void*)VTb, 0, 0LL, 256, 1.0f);
  gemm_nt_kernel<0><<<dim3(32, 8, 8), 256, 0, stream>>>(
      Qall, 1024, (long long)(1024 * 1024), Kall, 1024, (long long)(4096 * 1024),
      (void*)attn_mean, 4096, (long long)4096 * 1024, 1024, 0.25f);
  attn_kernel<<<dim3(1024, 1, 1), 256, 0, stream>>>(Qall, Kall, VTb, Opart, lpart);
  combine_kernel<<<dim3(16, NH, NBATCH), 256, 0, stream>>>(Opart, lpart, Oall);
  gemm_nt_kernel<0><<<dim3(2, 64, 1), 256, 0, stream>>>(
      Oall, 1024, 0LL, Wfc_b, 1024, 0LL, (void*)fcout, 256, 0LL, 1024, 1.0f);
  fc_ln_kernel<<<2048, 256, 0, stream>>>(fcout, tgt, lng, lnb, y);
}

// Round 3
// 706.810 us; speedup vs baseline: 1.0234x; 1.0234x over previous
//
#include <hip/hip_runtime.h>
#include <cstdint>
#include <cstddef>

#define LQ 1024
#define LK 4096
#define NBATCH 8
#define DM 256
#define NH 4

typedef __attribute__((ext_vector_type(8))) __bf16 bf16x8;
typedef __attribute__((ext_vector_type(4))) float f32x4;
typedef __attribute__((ext_vector_type(4))) unsigned int u32x4;
typedef __attribute__((ext_vector_type(4))) short s16x4;

__device__ __forceinline__ unsigned short f2bf(float f) {
  unsigned int u = __builtin_bit_cast(unsigned int, f);
  u += 0x7FFFu + ((u >> 16) & 1u);  // RNE
  return (unsigned short)(u >> 16);
}
__device__ __forceinline__ unsigned pack2(float a, float b) {
  return (unsigned)f2bf(a) | ((unsigned)f2bf(b) << 16);
}
__device__ __forceinline__ bf16x8 ld_bf8(const unsigned short* p) {
  u32x4 u = *reinterpret_cast<const u32x4*>(p);
  return __builtin_bit_cast(bf16x8, u);
}
__device__ __forceinline__ f32x4 zero4() {
  f32x4 v; v.x = 0.f; v.y = 0.f; v.z = 0.f; v.w = 0.f; return v;
}

// async global->LDS, 16B per lane; LDS dest = wave-uniform base + lane*16
#define ASYNC16(ldsp, gp)                                                      \
  __builtin_amdgcn_global_load_lds(                                            \
      (const __attribute__((address_space(1))) unsigned int*)(gp),             \
      (__attribute__((address_space(3))) unsigned int*)(ldsp), 16, 0, 0)

// ---------------------------------------------------------------------------
// prep (x8 vectorized): out[(b*L+l)*256+d] = bf16(a[(l*8+b)*256+d] (+badd))
// ---------------------------------------------------------------------------
__global__ void prep_add_kernel(const float* __restrict__ a,
                                const float* __restrict__ badd,
                                unsigned short* __restrict__ out,
                                int L, int n8) {
  int i = blockIdx.x * blockDim.x + threadIdx.x;
  if (i >= n8) return;
  int base = i * 8;
  int d = base & 255;
  int rest = base >> 8;
  int bb = rest & 7, l = rest >> 3;
  f32x4 x0 = *reinterpret_cast<const f32x4*>(a + base);
  f32x4 x1 = *reinterpret_cast<const f32x4*>(a + base + 4);
  if (badd) {
    f32x4 y0 = *reinterpret_cast<const f32x4*>(badd + base);
    f32x4 y1 = *reinterpret_cast<const f32x4*>(badd + base + 4);
    x0 += y0; x1 += y1;
  }
  u32x4 o;
  o.x = pack2(x0.x, x0.y); o.y = pack2(x0.z, x0.w);
  o.z = pack2(x1.x, x1.y); o.w = pack2(x1.z, x1.w);
  *reinterpret_cast<u32x4*>(out + (((size_t)bb * L + l) << 8) + d) = o;
}

__global__ void conv_bf16_kernel(const float* __restrict__ src,
                                 unsigned short* __restrict__ dst, int n8) {
  int i = blockIdx.x * blockDim.x + threadIdx.x;
  if (i >= n8) return;
  int base = i * 8;
  f32x4 x0 = *reinterpret_cast<const f32x4*>(src + base);
  f32x4 x1 = *reinterpret_cast<const f32x4*>(src + base + 4);
  u32x4 o;
  o.x = pack2(x0.x, x0.y); o.y = pack2(x0.z, x0.w);
  o.z = pack2(x1.x, x1.y); o.w = pack2(x1.z, x1.w);
  *reinterpret_cast<u32x4*>(dst + base) = o;
}

// ---------------------------------------------------------------------------
// NT GEMM (unchanged): global_load_lds(16B), XOR-swizzled LDS.
// ---------------------------------------------------------------------------
template <int OUT_MODE>
__global__ void __launch_bounds__(256)
gemm_nt_kernel(const unsigned short* __restrict__ A, int lda, long long sA,
               const unsigned short* __restrict__ B, int ldb, long long sB,
               void* __restrict__ Cv, int ldc, long long sC,
               int K, float alpha) {
  __shared__ __align__(16) unsigned short As[128 * 64];
  __shared__ __align__(16) unsigned short Bs[128 * 64];
  const int t = threadIdx.x;
  const int bm0 = blockIdx.y * 128;
  const int bn0 = blockIdx.x * 128;
  A += (size_t)blockIdx.z * sA + (size_t)bm0 * lda;
  B += (size_t)blockIdx.z * sB + (size_t)bn0 * ldb;
  const int lane = t & 63, w = t >> 6;
  const int wm = (w >> 1) * 64, wn = (w & 1) * 64;
  const int lr = lane & 15, quad = lane >> 4;
  const int srl = lane >> 3;
  const int sc = (lane & 7) ^ (srl & 7);

  f32x4 acc[4][4];
#pragma unroll
  for (int i = 0; i < 4; ++i)
#pragma unroll
    for (int j = 0; j < 4; ++j) acc[i][j] = zero4();

  for (int k0 = 0; k0 < K; k0 += 64) {
#pragma unroll
    for (int i = 0; i < 4; ++i) {
      int r0 = w * 32 + i * 8;
      ASYNC16(&As[r0 * 64], &A[(size_t)(r0 + srl) * lda + k0 + sc * 8]);
      ASYNC16(&Bs[r0 * 64], &B[(size_t)(r0 + srl) * ldb + k0 + sc * 8]);
    }
    __syncthreads();
#pragma unroll
    for (int ks = 0; ks < 2; ++ks) {
      bf16x8 af[4], bfv[4];
#pragma unroll
      for (int i = 0; i < 4; ++i) {
        int m = wm + i * 16 + lr;
        int pc = (ks * 4 + quad) ^ (lr & 7);
        af[i] = ld_bf8(&As[m * 64 + pc * 8]);
      }
#pragma unroll
      for (int j = 0; j < 4; ++j) {
        int n = wn + j * 16 + lr;
        int pc = (ks * 4 + quad) ^ (lr & 7);
        bfv[j] = ld_bf8(&Bs[n * 64 + pc * 8]);
      }
#pragma unroll
      for (int i = 0; i < 4; ++i)
#pragma unroll
        for (int j = 0; j < 4; ++j)
          acc[i][j] = __builtin_amdgcn_mfma_f32_16x16x32_bf16(af[i], bfv[j], acc[i][j], 0, 0, 0);
    }
    __syncthreads();
  }

  if (OUT_MODE == 0) {
    float* C = (float*)Cv + (size_t)blockIdx.z * sC;
#pragma unroll
    for (int i = 0; i < 4; ++i) {
      int m0 = bm0 + wm + i * 16 + quad * 4;
#pragma unroll
      for (int j = 0; j < 4; ++j) {
        int n = bn0 + wn + j * 16 + lr;
#pragma unroll
        for (int r = 0; r < 4; ++r)
          C[(size_t)(m0 + r) * ldc + n] = acc[i][j][r] * alpha;
      }
    }
  } else if (OUT_MODE == 1) {
    unsigned short* C = (unsigned short*)Cv + (size_t)blockIdx.z * sC;
#pragma unroll
    for (int i = 0; i < 4; ++i) {
      int m0 = bm0 + wm + i * 16 + quad * 4;
#pragma unroll
      for (int j = 0; j < 4; ++j) {
        int n = bn0 + wn + j * 16 + lr;
#pragma unroll
        for (int r = 0; r < 4; ++r)
          C[(size_t)(m0 + r) * ldc + n] = f2bf(acc[i][j][r] * alpha);
      }
    }
  } else {
    unsigned short* C = (unsigned short*)Cv;
#pragma unroll
    for (int i = 0; i < 4; ++i) {
      int m0 = bm0 + wm + i * 16 + quad * 4;
      int bb = m0 >> 12;
      int kp = m0 & 4095;
#pragma unroll
      for (int j = 0; j < 4; ++j) {
        int n = bn0 + wn + j * 16 + lr;
        s16x4 pk;
#pragma unroll
        for (int r = 0; r < 4; ++r) pk[r] = (short)f2bf(acc[i][j][r] * alpha);
        *reinterpret_cast<s16x4*>(&C[((size_t)(bb * 1024 + n)) * 4096 + kp]) = pk;
      }
    }
  }
}

// ---------------------------------------------------------------------------
// Flash attention v5 = round-1 structure (known-good 202us: single barrier per
// k-tile, prefetch issued at tile top so the whole tile's compute covers the
// load latency before the barrier's vmcnt(0) drain) + two grafts proven in v4:
//   (a) XCD-grouping block decode: all 8 qt-blocks of a (b,h,ks) KV slab land
//       on one XCD (2MB slab vs 4MB L2). v4 measured FETCH 300MB -> 83MB.
//   (b) s_setprio(1) around MFMA clusters (T5; +4-7% attn per m191).
// v4 lesson (302us regression): adding a second barrier after ISSUE_V exposes
// full V-load latency per tile (vmcnt(0) with no covering compute), and S[2]
// halves QK ILP. Do not reintroduce.
// ---------------------------------------------------------------------------
__global__ void __launch_bounds__(256, 2)
attn_kernel(const unsigned short* __restrict__ Qg,
            const unsigned short* __restrict__ Kg,
            const unsigned short* __restrict__ VTg,
            unsigned short* __restrict__ Opart,
            float* __restrict__ lpart) {
  __shared__ __align__(16) unsigned short Kt[2][32 * 256];  // [kpos][d], chunk^ (row&7)
  __shared__ __align__(16) unsigned short Vt[2][256 * 32];  // [e][kpos], chunk^ ((row>>1)&3)
  const int t = threadIdx.x;
  // XCD-grouping decode (512 blocks): lin&7 constant for all 8 qt-blocks of a
  // slab (round-robin dispatch -> same XCD); qt varies fastest in dispatch
  // order so early-resident blocks of an XCD share one slab.
  const int lin = blockIdx.x;
  const int xcd = lin & 7;
  const int blk = lin >> 3;        // 0..63
  const int qt = blk & 7;          // 8 q-tiles of 128 rows
  const int shi = blk >> 3;        // 0..7
  const int s_id = xcd + 8 * shi;  // 0..63 slab id
  const int ks = s_id & 1, h = (s_id >> 1) & 3, b = s_id >> 3;
  const int lane = t & 63, w = t >> 6;
  const int lr = lane & 15, quad = lane >> 4;

  // Q B-frags: qf[nt][s]: q = qt*128+w*32+nt*16+lr, d = s*32 + quad*8..+7
  const unsigned short* Qrow0 =
      Qg + ((size_t)(b * 1024 + qt * 128 + w * 32 + lr)) * 1024 + h * 256;
  bf16x8 qf[2][8];
#pragma unroll
  for (int s = 0; s < 8; ++s) {
    qf[0][s] = ld_bf8(&Qrow0[s * 32 + quad * 8]);
    qf[1][s] = ld_bf8(&Qrow0[16 * 1024 + s * 32 + quad * 8]);
  }

  f32x4 Oacc[16][2];
#pragma unroll
  for (int m2 = 0; m2 < 16; ++m2) {
    Oacc[m2][0] = zero4();
    Oacc[m2][1] = zero4();
  }
  float lsum_r[2] = {0.f, 0.f};

  const unsigned short* Kb =
      Kg + ((size_t)(b * 4096 + ks * 2048)) * 1024 + h * 256;
  const unsigned short* Vb =
      VTg + ((size_t)(b * 1024 + h * 256)) * 4096 + ks * 2048;

  // staging index precompute
  const int k_rsub = lane >> 5;                 // row within pair
  const int k_chunk = lane & 31;                // phys chunk (of 32)
  const int v_rsub = lane >> 2;                 // row within 16
  const int v_chunk = lane & 3;                 // phys chunk (of 4)

#define ISSUE_TILE(kt, bufsel)                                                 \
  {                                                                            \
    _Pragma("unroll") for (int i = 0; i < 4; ++i) {                            \
      int r0 = w * 8 + i * 2;                                                  \
      int krow = r0 + k_rsub;                                                  \
      int kc = k_chunk ^ (krow & 7);                                           \
      ASYNC16(&Kt[bufsel][r0 * 256], &Kb[(size_t)((kt) + krow) * 1024 + kc * 8]); \
      int vr0 = (w * 4 + i) * 16;                                              \
      int ve = vr0 + v_rsub;                                                   \
      int vc = v_chunk ^ ((ve >> 1) & 3);                                      \
      ASYNC16(&Vt[bufsel][vr0 * 32], &Vb[(size_t)ve * 4096 + (kt) + vc * 8]);  \
    }                                                                          \
  }

  ISSUE_TILE(0, 0)
  __syncthreads();

  const int bpermA = (((quad & 1) * 32) + lr) * 4;  // src lane qs0*16+lr, bytes
  const int bpermB = bpermA + 64;                   // qs0+1

  for (int kt = 0; kt < 2048; kt += 32) {
    const int pbuf = (kt >> 5) & 1;
    // prefetch next tile into the other buffer (tail prefetch reads junk into
    // a never-read buffer; addresses stay inside the workspace)
    ISSUE_TILE(kt + 32, pbuf ^ 1)

    const unsigned short* Ktp = Kt[pbuf];
    const unsigned short* Vtp = Vt[pbuf];

    // S^T[kpos][q]: A = K (m=kpos), B = Q regs. 2 m-tiles x 2 n-tiles, ILP 4.
    f32x4 S[2][2];
    S[0][0] = zero4(); S[0][1] = zero4();
    S[1][0] = zero4(); S[1][1] = zero4();
    __builtin_amdgcn_s_setprio(1);
#pragma unroll
    for (int s = 0; s < 8; ++s) {
      int pc = ((s * 4 + quad) ^ (lr & 7)) * 8;
      bf16x8 kf0 = ld_bf8(&Ktp[lr * 256 + pc]);
      bf16x8 kf1 = ld_bf8(&Ktp[(16 + lr) * 256 + pc]);
      S[0][0] = __builtin_amdgcn_mfma_f32_16x16x32_bf16(kf0, qf[0][s], S[0][0], 0, 0, 0);
      S[0][1] = __builtin_amdgcn_mfma_f32_16x16x32_bf16(kf0, qf[1][s], S[0][1], 0, 0, 0);
      S[1][0] = __builtin_amdgcn_mfma_f32_16x16x32_bf16(kf1, qf[0][s], S[1][0], 0, 0, 0);
      S[1][1] = __builtin_amdgcn_mfma_f32_16x16x32_bf16(kf1, qf[1][s], S[1][1], 0, 0, 0);
    }
    __builtin_amdgcn_s_setprio(0);

    // exp + pack to bf16 pairs
    unsigned pk[2][2][2];
#pragma unroll
    for (int mt = 0; mt < 2; ++mt)
#pragma unroll
      for (int nt = 0; nt < 2; ++nt) {
        float p0 = __expf(S[mt][nt][0]);
        float p1 = __expf(S[mt][nt][1]);
        float p2 = __expf(S[mt][nt][2]);
        float p3 = __expf(S[mt][nt][3]);
        lsum_r[nt] += (p0 + p1) + (p2 + p3);
        pk[mt][nt][0] = pack2(p0, p1);
        pk[mt][nt][1] = pack2(p2, p3);
      }

    // P^T C-layout -> B-operand A..: dest lane (lr,quad) elem j needs
    // kpos=quad*8+j, q=nt*16+lr  => src tile mt=quad>>1, src quad
    // (quad&1)*2+(j>>2), reg j&3.  ds_bpermute both tiles + select.
    bf16x8 pfrag[2];
#pragma unroll
    for (int nt = 0; nt < 2; ++nt) {
      u32x4 bfw;
#pragma unroll
      for (int w2 = 0; w2 < 2; ++w2) {
        int f0 = __builtin_amdgcn_ds_bpermute(bpermA, (int)pk[0][nt][w2]);
        int f1 = __builtin_amdgcn_ds_bpermute(bpermA, (int)pk[1][nt][w2]);
        bfw[w2] = (unsigned)(quad < 2 ? f0 : f1);
        int g0 = __builtin_amdgcn_ds_bpermute(bpermB, (int)pk[0][nt][w2]);
        int g1 = __builtin_amdgcn_ds_bpermute(bpermB, (int)pk[1][nt][w2]);
        bfw[2 + w2] = (unsigned)(quad < 2 ? g0 : g1);
      }
      pfrag[nt] = __builtin_bit_cast(bf16x8, bfw);
    }

    // PV: O^T[e][q] += V^T * P^T ; A = V^T (m=e), k = 32 kpos, 1 k-step
    __builtin_amdgcn_s_setprio(1);
#pragma unroll
    for (int m2 = 0; m2 < 16; ++m2) {
      bf16x8 vf = ld_bf8(&Vtp[(m2 * 16 + lr) * 32 + (quad ^ ((lr >> 1) & 3)) * 8]);
      Oacc[m2][0] = __builtin_amdgcn_mfma_f32_16x16x32_bf16(vf, pfrag[0], Oacc[m2][0], 0, 0, 0);
      Oacc[m2][1] = __builtin_amdgcn_mfma_f32_16x16x32_bf16(vf, pfrag[1], Oacc[m2][1], 0, 0, 0);
    }
    __builtin_amdgcn_s_setprio(0);
    __syncthreads();
  }
#undef ISSUE_TILE

  const int pidx = b * 4 + h;
  // lsum: reduce across quads (q lives in lr; partials spread over quad)
#pragma unroll
  for (int nt = 0; nt < 2; ++nt) {
    float l = lsum_r[nt];
    l += __shfl_xor(l, 16, 64);
    l += __shfl_xor(l, 32, 64);
    if (quad == 0)
      lpart[((size_t)(ks * 32 + pidx)) * 1024 + qt * 128 + w * 32 + nt * 16 + lr] = l;
  }

  // Opart[ks][p][e][q] bf16 (same format as combine expects)
  const size_t base = ((size_t)(ks * 32 + pidx)) * 256 * 1024;
  const int qg0 = qt * 128 + w * 32 + lr;
#pragma unroll
  for (int m2 = 0; m2 < 16; ++m2) {
#pragma unroll
    for (int nt = 0; nt < 2; ++nt) {
#pragma unroll
      for (int r = 0; r < 4; ++r) {
        int e = m2 * 16 + quad * 4 + r;
        Opart[base + (size_t)e * 1024 + qg0 + nt * 16] = f2bf(Oacc[m2][nt][r]);
      }
    }
  }
}

// ---------------------------------------------------------------------------
// combine: O = (Oa+Ob)/(la+lb), transpose [e][q] -> row-major [q][h*256+e]
// ---------------------------------------------------------------------------
__global__ void __launch_bounds__(256)
combine_kernel(const unsigned short* __restrict__ Opart,
               const float* __restrict__ lpart,
               unsigned short* __restrict__ Oall) {
  __shared__ float rl[64];
  __shared__ __align__(16) unsigned short T[64][264];
  const int t = threadIdx.x;
  const int qt = blockIdx.x, h = blockIdx.y, b = blockIdx.z;
  const int p = b * 4 + h;
  const int q0 = qt * 64;
  const size_t slabO = (size_t)32 * 256 * 1024;
  const size_t slabL = (size_t)32 * 1024;
  if (t < 64) {
    float la = lpart[(size_t)p * 1024 + q0 + t];
    float lb = lpart[slabL + (size_t)p * 1024 + q0 + t];
    rl[t] = 1.f / (la + lb);
  }
  __syncthreads();
  const int er = t >> 3, q8 = t & 7;
#pragma unroll
  for (int ei = 0; ei < 8; ++ei) {
    int e = ei * 32 + er;
    size_t idx = ((size_t)p * 256 + e) * 1024 + q0 + q8 * 8;
    u32x4 ua = *reinterpret_cast<const u32x4*>(&Opart[idx]);
    u32x4 ub = *reinterpret_cast<const u32x4*>(&Opart[slabO + idx]);
#pragma unroll
    for (int wd = 0; wd < 4; ++wd) {
      unsigned a = ((const unsigned*)&ua)[wd], bb2 = ((const unsigned*)&ub)[wd];
      float a0 = __builtin_bit_cast(float, a << 16);
      float a1 = __builtin_bit_cast(float, a & 0xFFFF0000u);
      float b0 = __builtin_bit_cast(float, bb2 << 16);
      float b1 = __builtin_bit_cast(float, bb2 & 0xFFFF0000u);
      int qA = q8 * 8 + wd * 2;
      T[qA + 0][e] = f2bf((a0 + b0) * rl[qA + 0]);
      T[qA + 1][e] = f2bf((a1 + b1) * rl[qA + 1]);
    }
  }
  __syncthreads();
  const int ql = t >> 2, ec = t & 3;
  const size_t orow = ((size_t)(b * 1024 + q0 + ql)) * 1024 + h * 256;
#pragma unroll
  for (int i = 0; i < 8; ++i) {
    int ch = ec * 8 + i;
    *reinterpret_cast<u32x4*>(&Oall[orow + ch * 8]) =
        *reinterpret_cast<const u32x4*>(&T[ql][ch * 8]);
  }
}

// ---------------------------------------------------------------------------
// residual + LayerNorm: one wave per row of 256
// ---------------------------------------------------------------------------
__global__ void __launch_bounds__(256)
fc_ln_kernel(const float* __restrict__ fc, const float* __restrict__ tgt,
             const float* __restrict__ g, const float* __restrict__ bb,
             float* __restrict__ y) {
  int row = blockIdx.x * 4 + (threadIdx.x >> 6);
  int lane = threadIdx.x & 63;
  int b = row >> 10, q = row & 1023;
  const float* fr = fc + (size_t)row * 256;
  const float* tr = tgt + ((size_t)(q * 8 + b)) * 256;
  float x[4];
  float s = 0.f, ss = 0.f;
#pragma unroll
  for (int e = 0; e < 4; ++e) {
    x[e] = fr[lane + e * 64] + tr[lane + e * 64];
    s += x[e];
    ss += x[e] * x[e];
  }
#pragma unroll
  for (int d = 1; d < 64; d <<= 1) {
    s += __shfl_xor(s, d, 64);
    ss += __shfl_xor(ss, d, 64);
  }
  float mu = s * (1.f / 256.f);
  float var = ss * (1.f / 256.f) - mu * mu;
  float rs = rsqrtf(var + 1e-5f);
  float* yr = y + ((size_t)(q * 8 + b)) * 256;
#pragma unroll
  for (int e = 0; e < 4; ++e)
    yr[lane + e * 64] = (x[e] - mu) * rs * g[lane + e * 64] + bb[lane + e * 64];
}

// ---------------------------------------------------------------------------
extern "C" void kernel_launch(void* const* d_in, const int* in_sizes, int n_in,
                              void* d_out, int out_size, void* d_ws, size_t ws_size,
                              hipStream_t stream) {
  (void)in_sizes; (void)n_in; (void)out_size; (void)ws_size;
  const float* tgt    = (const float*)d_in[0];
  const float* memory = (const float*)d_in[1];
  const float* pos    = (const float*)d_in[2];
  const float* qpos   = (const float*)d_in[3];
  const float* Wq     = (const float*)d_in[4];
  const float* Wk     = (const float*)d_in[5];
  const float* Wv     = (const float*)d_in[6];
  const float* Wfc    = (const float*)d_in[7];
  const float* lng    = (const float*)d_in[8];
  const float* lnb    = (const float*)d_in[9];
  float* out = (float*)d_out;

  char* ws = (char*)d_ws;
  const size_t MB = 1024 * 1024;
  unsigned short* Wq_b  = (unsigned short*)(ws + 0);
  unsigned short* Wk_b  = (unsigned short*)(ws + 512 * 1024);
  unsigned short* Wv_b  = (unsigned short*)(ws + 1 * MB);
  unsigned short* Wfc_b = (unsigned short*)(ws + 1 * MB + 512 * 1024);
  unsigned short* A_q   = (unsigned short*)(ws + 2 * MB);
  unsigned short* A_k   = (unsigned short*)(ws + 6 * MB);
  unsigned short* A_v   = (unsigned short*)(ws + 22 * MB);
  unsigned short* Qall  = (unsigned short*)(ws + 38 * MB);
  unsigned short* Kall  = (unsigned short*)(ws + 54 * MB);
  unsigned short* VTb   = (unsigned short*)(ws + 118 * MB);
  unsigned short* Opart = (unsigned short*)(ws + 2 * MB);
  float* lpart          = (float*)(ws + 36 * MB);
  unsigned short* Oall  = (unsigned short*)(ws + 118 * MB);
  float* fcout          = (float*)(ws + 140 * MB);
  float* y = out;
  float* attn_mean = out + (size_t)LQ * NBATCH * DM;

  int n_q = LQ * NBATCH * DM;
  int n_k = LK * NBATCH * DM;
  prep_add_kernel<<<(n_q / 8 + 255) / 256, 256, 0, stream>>>(tgt, qpos, A_q, LQ, n_q / 8);
  prep_add_kernel<<<(n_k / 8 + 255) / 256, 256, 0, stream>>>(memory, pos, A_k, LK, n_k / 8);
  prep_add_kernel<<<(n_k / 8 + 255) / 256, 256, 0, stream>>>(memory, nullptr, A_v, LK, n_k / 8);
  int n_w8 = 1024 * 256 / 8;
  conv_bf16_kernel<<<(n_w8 + 255) / 256, 256, 0, stream>>>(Wq, Wq_b, n_w8);
  conv_bf16_kernel<<<(n_w8 + 255) / 256, 256, 0, stream>>>(Wk, Wk_b, n_w8);
  conv_bf16_kernel<<<(n_w8 + 255) / 256, 256, 0, stream>>>(Wv, Wv_b, n_w8);
  conv_bf16_kernel<<<(n_w8 + 255) / 256, 256, 0, stream>>>(Wfc, Wfc_b, n_w8);

  gemm_nt_kernel<1><<<dim3(8, 64, 1), 256, 0, stream>>>(
      A_q, 256, 0LL, Wq_b, 256, 0LL, (void*)Qall, 1024, 0LL, 256, 0.0625f);
  gemm_nt_kernel<1><<<dim3(8, 256, 1), 256, 0, stream>>>(
      A_k, 256, 0LL, Wk_b, 256, 0LL, (void*)Kall, 1024, 0LL, 256, 1.0f);
  gemm_nt_kernel<2><<<dim3(8, 256, 1), 256, 0, stream>>>(
      A_v, 256, 0LL, Wv_b, 256, 0LL, (void*)VTb, 0, 0LL, 256, 1.0f);
  gemm_nt_kernel<0><<<dim3(32, 8, 8), 256, 0, stream>>>(
      Qall, 1024, (long long)(1024 * 1024), Kall, 1024, (long long)(4096 * 1024),
      (void*)attn_mean, 4096, (long long)4096 * 1024, 1024, 0.25f);
  attn_kernel<<<dim3(512, 1, 1), 256, 0, stream>>>(Qall, Kall, VTb, Opart, lpart);
  combine_kernel<<<dim3(16, NH, NBATCH), 256, 0, stream>>>(Opart, lpart, Oall);
  gemm_nt_kernel<0><<<dim3(2, 64, 1), 256, 0, stream>>>(
      Oall, 1024, 0LL, Wfc_b, 1024, 0LL, (void*)fcout, 256, 0LL, 1024, 1.0f);
  fc_ln_kernel<<<2048, 256, 0, stream>>>(fcout, tgt, lng, lnb, y);
}

// Round 7
// 588.798 us; speedup vs baseline: 1.2285x; 1.2004x over previous
//
#include <hip/hip_runtime.h>
#include <cstdint>
#include <cstddef>

#define LQ 1024
#define LK 4096
#define NBATCH 8
#define DM 256
#define NH 4

typedef __attribute__((ext_vector_type(8))) __bf16 bf16x8;
typedef __attribute__((ext_vector_type(4))) float f32x4;
typedef __attribute__((ext_vector_type(4))) unsigned int u32x4;
typedef __attribute__((ext_vector_type(4))) short s16x4;

__device__ __forceinline__ unsigned short f2bf(float f) {
  unsigned int u = __builtin_bit_cast(unsigned int, f);
  u += 0x7FFFu + ((u >> 16) & 1u);  // RNE
  return (unsigned short)(u >> 16);
}
__device__ __forceinline__ unsigned pack2(float a, float b) {
  return (unsigned)f2bf(a) | ((unsigned)f2bf(b) << 16);
}
__device__ __forceinline__ bf16x8 ld_bf8(const unsigned short* p) {
  u32x4 u = *reinterpret_cast<const u32x4*>(p);
  return __builtin_bit_cast(bf16x8, u);
}
__device__ __forceinline__ f32x4 zero4() {
  f32x4 v; v.x = 0.f; v.y = 0.f; v.z = 0.f; v.w = 0.f; return v;
}

// async global->LDS, 16B per lane; LDS dest = wave-uniform base + lane*16
#define ASYNC16(ldsp, gp)                                                      \
  __builtin_amdgcn_global_load_lds(                                            \
      (const __attribute__((address_space(1))) unsigned int*)(gp),             \
      (__attribute__((address_space(3))) unsigned int*)(ldsp), 16, 0, 0)

// ---------------------------------------------------------------------------
// prep (x8 vectorized): out[(b*L+l)*256+d] = bf16(a[(l*8+b)*256+d] (+badd))
// ---------------------------------------------------------------------------
__global__ void prep_add_kernel(const float* __restrict__ a,
                                const float* __restrict__ badd,
                                unsigned short* __restrict__ out,
                                int L, int n8) {
  int i = blockIdx.x * blockDim.x + threadIdx.x;
  if (i >= n8) return;
  int base = i * 8;
  int d = base & 255;
  int rest = base >> 8;
  int bb = rest & 7, l = rest >> 3;
  f32x4 x0 = *reinterpret_cast<const f32x4*>(a + base);
  f32x4 x1 = *reinterpret_cast<const f32x4*>(a + base + 4);
  if (badd) {
    f32x4 y0 = *reinterpret_cast<const f32x4*>(badd + base);
    f32x4 y1 = *reinterpret_cast<const f32x4*>(badd + base + 4);
    x0 += y0; x1 += y1;
  }
  u32x4 o;
  o.x = pack2(x0.x, x0.y); o.y = pack2(x0.z, x0.w);
  o.z = pack2(x1.x, x1.y); o.w = pack2(x1.z, x1.w);
  *reinterpret_cast<u32x4*>(out + (((size_t)bb * L + l) << 8) + d) = o;
}

__global__ void conv_bf16_kernel(const float* __restrict__ src,
                                 unsigned short* __restrict__ dst, int n8) {
  int i = blockIdx.x * blockDim.x + threadIdx.x;
  if (i >= n8) return;
  int base = i * 8;
  f32x4 x0 = *reinterpret_cast<const f32x4*>(src + base);
  f32x4 x1 = *reinterpret_cast<const f32x4*>(src + base + 4);
  u32x4 o;
  o.x = pack2(x0.x, x0.y); o.y = pack2(x0.z, x0.w);
  o.z = pack2(x1.x, x1.y); o.w = pack2(x1.z, x1.w);
  *reinterpret_cast<u32x4*>(dst + base) = o;
}

// ---------------------------------------------------------------------------
// W transpose: in f32 [1024 he][256 d] -> out bf16 [256 d][1024 he]
// grid (16,4): he0 = bx*64, d0 = by*64; 256 threads; LDS 64x65 f32.
// ---------------------------------------------------------------------------
__global__ void __launch_bounds__(256)
transpose_w_kernel(const float* __restrict__ in, unsigned short* __restrict__ out) {
  __shared__ float ts[64][65];
  const int t = threadIdx.x;
  const int he0 = blockIdx.x * 64, d0 = blockIdx.y * 64;
  const int rh = t >> 6, c = t & 63;
#pragma unroll
  for (int i = 0; i < 16; ++i) {
    int r = i * 4 + rh;
    ts[r][c] = in[(size_t)(he0 + r) * 256 + d0 + c];
  }
  __syncthreads();
#pragma unroll
  for (int i = 0; i < 16; ++i) {
    int r = i * 4 + rh;  // d-local
    out[(size_t)(d0 + r) * 1024 + he0 + c] = f2bf(ts[c][r]);
  }
}

// ---------------------------------------------------------------------------
// NT GEMM (unchanged): global_load_lds(16B), XOR-swizzled LDS.
// C[m][n] = alpha * sum_k A[m][k]*B[n][k]
// ---------------------------------------------------------------------------
template <int OUT_MODE>
__global__ void __launch_bounds__(256)
gemm_nt_kernel(const unsigned short* __restrict__ A, int lda, long long sA,
               const unsigned short* __restrict__ B, int ldb, long long sB,
               void* __restrict__ Cv, int ldc, long long sC,
               int K, float alpha) {
  __shared__ __align__(16) unsigned short As[128 * 64];
  __shared__ __align__(16) unsigned short Bs[128 * 64];
  const int t = threadIdx.x;
  const int bm0 = blockIdx.y * 128;
  const int bn0 = blockIdx.x * 128;
  A += (size_t)blockIdx.z * sA + (size_t)bm0 * lda;
  B += (size_t)blockIdx.z * sB + (size_t)bn0 * ldb;
  const int lane = t & 63, w = t >> 6;
  const int wm = (w >> 1) * 64, wn = (w & 1) * 64;
  const int lr = lane & 15, quad = lane >> 4;
  const int srl = lane >> 3;
  const int sc = (lane & 7) ^ (srl & 7);

  f32x4 acc[4][4];
#pragma unroll
  for (int i = 0; i < 4; ++i)
#pragma unroll
    for (int j = 0; j < 4; ++j) acc[i][j] = zero4();

  for (int k0 = 0; k0 < K; k0 += 64) {
#pragma unroll
    for (int i = 0; i < 4; ++i) {
      int r0 = w * 32 + i * 8;
      ASYNC16(&As[r0 * 64], &A[(size_t)(r0 + srl) * lda + k0 + sc * 8]);
      ASYNC16(&Bs[r0 * 64], &B[(size_t)(r0 + srl) * ldb + k0 + sc * 8]);
    }
    __syncthreads();
#pragma unroll
    for (int ks = 0; ks < 2; ++ks) {
      bf16x8 af[4], bfv[4];
#pragma unroll
      for (int i = 0; i < 4; ++i) {
        int m = wm + i * 16 + lr;
        int pc = (ks * 4 + quad) ^ (lr & 7);
        af[i] = ld_bf8(&As[m * 64 + pc * 8]);
      }
#pragma unroll
      for (int j = 0; j < 4; ++j) {
        int n = wn + j * 16 + lr;
        int pc = (ks * 4 + quad) ^ (lr & 7);
        bfv[j] = ld_bf8(&Bs[n * 64 + pc * 8]);
      }
#pragma unroll
      for (int i = 0; i < 4; ++i)
#pragma unroll
        for (int j = 0; j < 4; ++j)
          acc[i][j] = __builtin_amdgcn_mfma_f32_16x16x32_bf16(af[i], bfv[j], acc[i][j], 0, 0, 0);
    }
    __syncthreads();
  }

  if (OUT_MODE == 0) {
    float* C = (float*)Cv + (size_t)blockIdx.z * sC;
#pragma unroll
    for (int i = 0; i < 4; ++i) {
      int m0 = bm0 + wm + i * 16 + quad * 4;
#pragma unroll
      for (int j = 0; j < 4; ++j) {
        int n = bn0 + wn + j * 16 + lr;
#pragma unroll
        for (int r = 0; r < 4; ++r)
          C[(size_t)(m0 + r) * ldc + n] = acc[i][j][r] * alpha;
      }
    }
  } else if (OUT_MODE == 1) {
    unsigned short* C = (unsigned short*)Cv + (size_t)blockIdx.z * sC;
#pragma unroll
    for (int i = 0; i < 4; ++i) {
      int m0 = bm0 + wm + i * 16 + quad * 4;
#pragma unroll
      for (int j = 0; j < 4; ++j) {
        int n = bn0 + wn + j * 16 + lr;
#pragma unroll
        for (int r = 0; r < 4; ++r)
          C[(size_t)(m0 + r) * ldc + n] = f2bf(acc[i][j][r] * alpha);
      }
    }
  } else {
    unsigned short* C = (unsigned short*)Cv;
#pragma unroll
    for (int i = 0; i < 4; ++i) {
      int m0 = bm0 + wm + i * 16 + quad * 4;
      int bb = m0 >> 12;
      int kp = m0 & 4095;
#pragma unroll
      for (int j = 0; j < 4; ++j) {
        int n = bn0 + wn + j * 16 + lr;
        s16x4 pk;
#pragma unroll
        for (int r = 0; r < 4; ++r) pk[r] = (short)f2bf(acc[i][j][r] * alpha);
        *reinterpret_cast<s16x4*>(&C[((size_t)(bb * 1024 + n)) * 4096 + kp]) = pk;
      }
    }
  }
}

// ---------------------------------------------------------------------------
// Flash attention (round-1 config, measured 202us — DO NOT regraft):
//   - single barrier per k-tile; prefetch of tile t+1 issued at tile top so the
//     whole tile's compute covers load latency before the barrier's vmcnt(0).
//   - NO XCD-grouping: R2/R3 showed grouping cuts FETCH 300->86MB but SLOWS the
//     kernel (202->247/302us): latency-bound; dispersed sharers are served by
//     L3 (K/V=128MB fits 256MB L3) with decorrelated misses.
//   - NO setprio (confounded regression R3; m190 neutral/negative on lockstep).
//   - V-swizzle key (row>>1)&3 (64B rows): conflicts 2.1e7 -> 1.26e7 (R1).
// grid (16=qt*2+ks, H, B), 256 thr = 4 waves; wave owns 32 q rows.
// ---------------------------------------------------------------------------
__global__ void __launch_bounds__(256, 2)
attn_kernel(const unsigned short* __restrict__ Qg,
            const unsigned short* __restrict__ Kg,
            const unsigned short* __restrict__ VTg,
            unsigned short* __restrict__ Opart,
            float* __restrict__ lpart) {
  __shared__ __align__(16) unsigned short Kt[2][32 * 256];  // [kpos][d], chunk^ (row&7)
  __shared__ __align__(16) unsigned short Vt[2][256 * 32];  // [e][kpos], chunk^ ((row>>1)&3)
  const int t = threadIdx.x;
  const int qt = blockIdx.x >> 1, ks = blockIdx.x & 1;
  const int h = blockIdx.y, b = blockIdx.z;
  const int lane = t & 63, w = t >> 6;
  const int lr = lane & 15, quad = lane >> 4;

  // Q B-frags: qf[nt][s]: q = qt*128+w*32+nt*16+lr, d = s*32 + quad*8..+7
  const unsigned short* Qrow0 =
      Qg + ((size_t)(b * 1024 + qt * 128 + w * 32 + lr)) * 1024 + h * 256;
  bf16x8 qf[2][8];
#pragma unroll
  for (int s = 0; s < 8; ++s) {
    qf[0][s] = ld_bf8(&Qrow0[s * 32 + quad * 8]);
    qf[1][s] = ld_bf8(&Qrow0[16 * 1024 + s * 32 + quad * 8]);
  }

  f32x4 Oacc[16][2];
#pragma unroll
  for (int m2 = 0; m2 < 16; ++m2) {
    Oacc[m2][0] = zero4();
    Oacc[m2][1] = zero4();
  }
  float lsum_r[2] = {0.f, 0.f};

  const unsigned short* Kb =
      Kg + ((size_t)(b * 4096 + ks * 2048)) * 1024 + h * 256;
  const unsigned short* Vb =
      VTg + ((size_t)(b * 1024 + h * 256)) * 4096 + ks * 2048;

  // staging index precompute
  const int k_rsub = lane >> 5;                 // row within pair
  const int k_chunk = lane & 31;                // phys chunk (of 32)
  const int v_rsub = lane >> 2;                 // row within 16
  const int v_chunk = lane & 3;                 // phys chunk (of 4)

#define ISSUE_TILE(kt, bufsel)                                                 \
  {                                                                            \
    _Pragma("unroll") for (int i = 0; i < 4; ++i) {                            \
      int r0 = w * 8 + i * 2;                                                  \
      int krow = r0 + k_rsub;                                                  \
      int kc = k_chunk ^ (krow & 7);                                           \
      ASYNC16(&Kt[bufsel][r0 * 256], &Kb[(size_t)((kt) + krow) * 1024 + kc * 8]); \
      int vr0 = (w * 4 + i) * 16;                                              \
      int ve = vr0 + v_rsub;                                                   \
      int vc = v_chunk ^ ((ve >> 1) & 3);                                      \
      ASYNC16(&Vt[bufsel][vr0 * 32], &Vb[(size_t)ve * 4096 + (kt) + vc * 8]);  \
    }                                                                          \
  }

  ISSUE_TILE(0, 0)
  __syncthreads();

  const int bpermA = (((quad & 1) * 32) + lr) * 4;  // src lane qs0*16+lr, bytes
  const int bpermB = bpermA + 64;                   // qs0+1

  for (int kt = 0; kt < 2048; kt += 32) {
    const int pbuf = (kt >> 5) & 1;
    // prefetch next tile into the other buffer (tail prefetch reads junk into
    // a never-read buffer; addresses stay inside the workspace)
    ISSUE_TILE(kt + 32, pbuf ^ 1)

    const unsigned short* Ktp = Kt[pbuf];
    const unsigned short* Vtp = Vt[pbuf];

    // S^T[kpos][q]: A = K (m=kpos), B = Q regs. 2 m-tiles x 2 n-tiles, ILP 4.
    f32x4 S[2][2];
    S[0][0] = zero4(); S[0][1] = zero4();
    S[1][0] = zero4(); S[1][1] = zero4();
#pragma unroll
    for (int s = 0; s < 8; ++s) {
      int pc = ((s * 4 + quad) ^ (lr & 7)) * 8;
      bf16x8 kf0 = ld_bf8(&Ktp[lr * 256 + pc]);
      bf16x8 kf1 = ld_bf8(&Ktp[(16 + lr) * 256 + pc]);
      S[0][0] = __builtin_amdgcn_mfma_f32_16x16x32_bf16(kf0, qf[0][s], S[0][0], 0, 0, 0);
      S[0][1] = __builtin_amdgcn_mfma_f32_16x16x32_bf16(kf0, qf[1][s], S[0][1], 0, 0, 0);
      S[1][0] = __builtin_amdgcn_mfma_f32_16x16x32_bf16(kf1, qf[0][s], S[1][0], 0, 0, 0);
      S[1][1] = __builtin_amdgcn_mfma_f32_16x16x32_bf16(kf1, qf[1][s], S[1][1], 0, 0, 0);
    }

    // exp + pack to bf16 pairs
    unsigned pk[2][2][2];
#pragma unroll
    for (int mt = 0; mt < 2; ++mt)
#pragma unroll
      for (int nt = 0; nt < 2; ++nt) {
        float p0 = __expf(S[mt][nt][0]);
        float p1 = __expf(S[mt][nt][1]);
        float p2 = __expf(S[mt][nt][2]);
        float p3 = __expf(S[mt][nt][3]);
        lsum_r[nt] += (p0 + p1) + (p2 + p3);
        pk[mt][nt][0] = pack2(p0, p1);
        pk[mt][nt][1] = pack2(p2, p3);
      }

    // P^T C-layout -> B-operand A..: dest lane (lr,quad) elem j needs
    // kpos=quad*8+j, q=nt*16+lr  => src tile mt=quad>>1, src quad
    // (quad&1)*2+(j>>2), reg j&3.  ds_bpermute both tiles + select.
    bf16x8 pfrag[2];
#pragma unroll
    for (int nt = 0; nt < 2; ++nt) {
      u32x4 bfw;
#pragma unroll
      for (int w2 = 0; w2 < 2; ++w2) {
        int f0 = __builtin_amdgcn_ds_bpermute(bpermA, (int)pk[0][nt][w2]);
        int f1 = __builtin_amdgcn_ds_bpermute(bpermA, (int)pk[1][nt][w2]);
        bfw[w2] = (unsigned)(quad < 2 ? f0 : f1);
        int g0 = __builtin_amdgcn_ds_bpermute(bpermB, (int)pk[0][nt][w2]);
        int g1 = __builtin_amdgcn_ds_bpermute(bpermB, (int)pk[1][nt][w2]);
        bfw[2 + w2] = (unsigned)(quad < 2 ? g0 : g1);
      }
      pfrag[nt] = __builtin_bit_cast(bf16x8, bfw);
    }

    // PV: O^T[e][q] += V^T * P^T ; A = V^T (m=e), k = 32 kpos, 1 k-step
#pragma unroll
    for (int m2 = 0; m2 < 16; ++m2) {
      bf16x8 vf = ld_bf8(&Vtp[(m2 * 16 + lr) * 32 + (quad ^ ((lr >> 1) & 3)) * 8]);
      Oacc[m2][0] = __builtin_amdgcn_mfma_f32_16x16x32_bf16(vf, pfrag[0], Oacc[m2][0], 0, 0, 0);
      Oacc[m2][1] = __builtin_amdgcn_mfma_f32_16x16x32_bf16(vf, pfrag[1], Oacc[m2][1], 0, 0, 0);
    }
    __syncthreads();
  }
#undef ISSUE_TILE

  const int pidx = b * 4 + h;
  // lsum: reduce across quads (q lives in lr; partials spread over quad)
#pragma unroll
  for (int nt = 0; nt < 2; ++nt) {
    float l = lsum_r[nt];
    l += __shfl_xor(l, 16, 64);
    l += __shfl_xor(l, 32, 64);
    if (quad == 0)
      lpart[((size_t)(ks * 32 + pidx)) * 1024 + qt * 128 + w * 32 + nt * 16 + lr] = l;
  }

  // Opart[ks][p][e][q] bf16 (same format as combine expects)
  const size_t base = ((size_t)(ks * 32 + pidx)) * 256 * 1024;
  const int qg0 = qt * 128 + w * 32 + lr;
#pragma unroll
  for (int m2 = 0; m2 < 16; ++m2) {
#pragma unroll
    for (int nt = 0; nt < 2; ++nt) {
#pragma unroll
      for (int r = 0; r < 4; ++r) {
        int e = m2 * 16 + quad * 4 + r;
        Opart[base + (size_t)e * 1024 + qg0 + nt * 16] = f2bf(Oacc[m2][nt][r]);
      }
    }
  }
}

// ---------------------------------------------------------------------------
// combine: O = (Oa+Ob)/(la+lb), transpose [e][q] -> row-major [q][h*256+e]
// ---------------------------------------------------------------------------
__global__ void __launch_bounds__(256)
combine_kernel(const unsigned short* __restrict__ Opart,
               const float* __restrict__ lpart,
               unsigned short* __restrict__ Oall) {
  __shared__ float rl[64];
  __shared__ __align__(16) unsigned short T[64][264];
  const int t = threadIdx.x;
  const int qt = blockIdx.x, h = blockIdx.y, b = blockIdx.z;
  const int p = b * 4 + h;
  const int q0 = qt * 64;
  const size_t slabO = (size_t)32 * 256 * 1024;
  const size_t slabL = (size_t)32 * 1024;
  if (t < 64) {
    float la = lpart[(size_t)p * 1024 + q0 + t];
    float lb = lpart[slabL + (size_t)p * 1024 + q0 + t];
    rl[t] = 1.f / (la + lb);
  }
  __syncthreads();
  const int er = t >> 3, q8 = t & 7;
#pragma unroll
  for (int ei = 0; ei < 8; ++ei) {
    int e = ei * 32 + er;
    size_t idx = ((size_t)p * 256 + e) * 1024 + q0 + q8 * 8;
    u32x4 ua = *reinterpret_cast<const u32x4*>(&Opart[idx]);
    u32x4 ub = *reinterpret_cast<const u32x4*>(&Opart[slabO + idx]);
#pragma unroll
    for (int wd = 0; wd < 4; ++wd) {
      unsigned a = ((const unsigned*)&ua)[wd], bb2 = ((const unsigned*)&ub)[wd];
      float a0 = __builtin_bit_cast(float, a << 16);
      float a1 = __builtin_bit_cast(float, a & 0xFFFF0000u);
      float b0 = __builtin_bit_cast(float, bb2 << 16);
      float b1 = __builtin_bit_cast(float, bb2 & 0xFFFF0000u);
      int qA = q8 * 8 + wd * 2;
      T[qA + 0][e] = f2bf((a0 + b0) * rl[qA + 0]);
      T[qA + 1][e] = f2bf((a1 + b1) * rl[qA + 1]);
    }
  }
  __syncthreads();
  const int ql = t >> 2, ec = t & 3;
  const size_t orow = ((size_t)(b * 1024 + q0 + ql)) * 1024 + h * 256;
#pragma unroll
  for (int i = 0; i < 8; ++i) {
    int ch = ec * 8 + i;
    *reinterpret_cast<u32x4*>(&Oall[orow + ch * 8]) =
        *reinterpret_cast<const u32x4*>(&T[ql][ch * 8]);
  }
}

// ---------------------------------------------------------------------------
// residual + LayerNorm: one wave per row of 256
// ---------------------------------------------------------------------------
__global__ void __launch_bounds__(256)
fc_ln_kernel(const float* __restrict__ fc, const float* __restrict__ tgt,
             const float* __restrict__ g, const float* __restrict__ bb,
             float* __restrict__ y) {
  int row = blockIdx.x * 4 + (threadIdx.x >> 6);
  int lane = threadIdx.x & 63;
  int b = row >> 10, q = row & 1023;
  const float* fr = fc + (size_t)row * 256;
  const float* tr = tgt + ((size_t)(q * 8 + b)) * 256;
  float x[4];
  float s = 0.f, ss = 0.f;
#pragma unroll
  for (int e = 0; e < 4; ++e) {
    x[e] = fr[lane + e * 64] + tr[lane + e * 64];
    s += x[e];
    ss += x[e] * x[e];
  }
#pragma unroll
  for (int d = 1; d < 64; d <<= 1) {
    s += __shfl_xor(s, d, 64);
    ss += __shfl_xor(ss, d, 64);
  }
  float mu = s * (1.f / 256.f);
  float var = ss * (1.f / 256.f) - mu * mu;
  float rs = rsqrtf(var + 1e-5f);
  float* yr = y + ((size_t)(q * 8 + b)) * 256;
#pragma unroll
  for (int e = 0; e < 4; ++e)
    yr[lane + e * 64] = (x[e] - mu) * rs * g[lane + e * 64] + bb[lane + e * 64];
}

// ---------------------------------------------------------------------------
// Workspace lifetime map (launch-ordered; ws >= 182MB proven by rounds 0-3).
//   L1-2  transpose      -> WqT[38,38.5) WkT[38.5,39)
//   L3    GT gemm        -> GT [39,39.125)          (reads WqT/WkT)
//   L4-5  prep           -> A_q[2,6) A_k[6,22)
//   L6    Tq gemm        -> Tq [22,26)              (reads A_q, GT)
//   L7    logits gemm    -> attn_mean (d_out)       (reads Tq, A_k)
//   L8    prep           -> A_v[22,38)              (kills Tq: dead)
//   L9-12 conv           -> W*_b [0,2)
//   L13   Qall gemm      -> [38,54)                 (kills WqT/WkT/GT: dead)
//   L14   Kall gemm      -> [54,118)
//   L15   VTb gemm       -> [118,182)               (kills A_v: last read)
//   L16   attn           -> Opart[2,34) lpart[36,36.25)
//   L17   combine        -> Oall[118,134)           (VTb dead)
//   L18   fc gemm        -> fcout[140,148);  L19 ln -> y (d_out)
// ---------------------------------------------------------------------------
extern "C" void kernel_launch(void* const* d_in, const int* in_sizes, int n_in,
                              void* d_out, int out_size, void* d_ws, size_t ws_size,
                              hipStream_t stream) {
  (void)in_sizes; (void)n_in; (void)out_size; (void)ws_size;
  const float* tgt    = (const float*)d_in[0];
  const float* memory = (const float*)d_in[1];
  const float* pos    = (const float*)d_in[2];
  const float* qpos   = (const float*)d_in[3];
  const float* Wq     = (const float*)d_in[4];
  const float* Wk     = (const float*)d_in[5];
  const float* Wv     = (const float*)d_in[6];
  const float* Wfc    = (const float*)d_in[7];
  const float* lng    = (const float*)d_in[8];
  const float* lnb    = (const float*)d_in[9];
  float* out = (float*)d_out;

  char* ws = (char*)d_ws;
  const size_t MB = 1024 * 1024;
  unsigned short* Wq_b  = (unsigned short*)(ws + 0);
  unsigned short* Wk_b  = (unsigned short*)(ws + 512 * 1024);
  unsigned short* Wv_b  = (unsigned short*)(ws + 1 * MB);
  unsigned short* Wfc_b = (unsigned short*)(ws + 1 * MB + 512 * 1024);
  unsigned short* A_q   = (unsigned short*)(ws + 2 * MB);
  unsigned short* A_k   = (unsigned short*)(ws + 6 * MB);
  unsigned short* A_v   = (unsigned short*)(ws + 22 * MB);
  unsigned short* Tq    = (unsigned short*)(ws + 22 * MB);                 // [22,26) before A_v
  unsigned short* Qall  = (unsigned short*)(ws + 38 * MB);
  unsigned short* WqT   = (unsigned short*)(ws + 38 * MB);                 // [38,38.5) before Qall
  unsigned short* WkT   = (unsigned short*)(ws + 38 * MB + 512 * 1024);    // [38.5,39)
  unsigned short* GT    = (unsigned short*)(ws + 39 * MB);                 // [39,39.125)
  unsigned short* Kall  = (unsigned short*)(ws + 54 * MB);
  unsigned short* VTb   = (unsigned short*)(ws + 118 * MB);
  unsigned short* Opart = (unsigned short*)(ws + 2 * MB);
  float* lpart          = (float*)(ws + 36 * MB);
  unsigned short* Oall  = (unsigned short*)(ws + 118 * MB);
  float* fcout          = (float*)(ws + 140 * MB);
  float* y = out;
  float* attn_mean = out + (size_t)LQ * NBATCH * DM;

  int n_q = LQ * NBATCH * DM;
  int n_k = LK * NBATCH * DM;
  int n_w8 = 1024 * 256 / 8;

  // --- factorized attn_mean path first (temps die before Qall/A_v writes) ---
  transpose_w_kernel<<<dim3(16, 4), 256, 0, stream>>>(Wq, WqT);
  transpose_w_kernel<<<dim3(16, 4), 256, 0, stream>>>(Wk, WkT);
  // GT[d'][d] = (scale/H) * sum_he Wk[he][d'] * Wq[he][d]   (256x256, K=1024)
  gemm_nt_kernel<1><<<dim3(2, 2, 1), 256, 0, stream>>>(
      WkT, 1024, 0LL, WqT, 1024, 0LL, (void*)GT, 256, 0LL, 1024, 0.015625f);
  prep_add_kernel<<<(n_q / 8 + 255) / 256, 256, 0, stream>>>(tgt, qpos, A_q, LQ, n_q / 8);
  prep_add_kernel<<<(n_k / 8 + 255) / 256, 256, 0, stream>>>(memory, pos, A_k, LK, n_k / 8);
  // Tq[bq][d'] = sum_d A_q[bq][d] * GT[d'][d]   (8192x256, K=256)
  gemm_nt_kernel<1><<<dim3(2, 64, 1), 256, 0, stream>>>(
      A_q, 256, 0LL, GT, 256, 0LL, (void*)Tq, 256, 0LL, 256, 1.0f);
  // attn_mean[b][q][k'] = sum_d' Tq[bq][d'] * A_k[bk'][d']  (K=256, was K=1024)
  gemm_nt_kernel<0><<<dim3(32, 8, 8), 256, 0, stream>>>(
      Tq, 256, (long long)(1024 * 256), A_k, 256, (long long)(4096 * 256),
      (void*)attn_mean, 4096, (long long)4096 * 1024, 256, 1.0f);

  // --- main path ---
  prep_add_kernel<<<(n_k / 8 + 255) / 256, 256, 0, stream>>>(memory, nullptr, A_v, LK, n_k / 8);
  conv_bf16_kernel<<<(n_w8 + 255) / 256, 256, 0, stream>>>(Wq, Wq_b, n_w8);
  conv_bf16_kernel<<<(n_w8 + 255) / 256, 256, 0, stream>>>(Wk, Wk_b, n_w8);
  conv_bf16_kernel<<<(n_w8 + 255) / 256, 256, 0, stream>>>(Wv, Wv_b, n_w8);
  conv_bf16_kernel<<<(n_w8 + 255) / 256, 256, 0, stream>>>(Wfc, Wfc_b, n_w8);

  gemm_nt_kernel<1><<<dim3(8, 64, 1), 256, 0, stream>>>(
      A_q, 256, 0LL, Wq_b, 256, 0LL, (void*)Qall, 1024, 0LL, 256, 0.0625f);
  gemm_nt_kernel<1><<<dim3(8, 256, 1), 256, 0, stream>>>(
      A_k, 256, 0LL, Wk_b, 256, 0LL, (void*)Kall, 1024, 0LL, 256, 1.0f);
  gemm_nt_kernel<2><<<dim3(8, 256, 1), 256, 0, stream>>>(
      A_v, 256, 0LL, Wv_b, 256, 0LL, (void*)VTb, 0, 0LL, 256, 1.0f);

  attn_kernel<<<dim3(16, NH, NBATCH), 256, 0, stream>>>(Qall, Kall, VTb, Opart, lpart);
  combine_kernel<<<dim3(16, NH, NBATCH), 256, 0, stream>>>(Opart, lpart, Oall);
  gemm_nt_kernel<0><<<dim3(2, 64, 1), 256, 0, stream>>>(
      Oall, 1024, 0LL, Wfc_b, 1024, 0LL, (void*)fcout, 256, 0LL, 1024, 1.0f);
  fc_ln_kernel<<<2048, 256, 0, stream>>>(fcout, tgt, lng, lnb, y);
}

// Round 8
// 580.592 us; speedup vs baseline: 1.2459x; 1.0141x over previous
//
#include <hip/hip_runtime.h>
#include <cstdint>
#include <cstddef>

#define LQ 1024
#define LK 4096
#define NBATCH 8
#define DM 256
#define NH 4

typedef __attribute__((ext_vector_type(8))) __bf16 bf16x8;
typedef __attribute__((ext_vector_type(4))) float f32x4;
typedef __attribute__((ext_vector_type(4))) unsigned int u32x4;
typedef __attribute__((ext_vector_type(4))) short s16x4;

__device__ __forceinline__ unsigned short f2bf(float f) {
  unsigned int u = __builtin_bit_cast(unsigned int, f);
  u += 0x7FFFu + ((u >> 16) & 1u);  // RNE
  return (unsigned short)(u >> 16);
}
__device__ __forceinline__ unsigned pack2(float a, float b) {
  return (unsigned)f2bf(a) | ((unsigned)f2bf(b) << 16);
}
__device__ __forceinline__ bf16x8 ld_bf8(const unsigned short* p) {
  u32x4 u = *reinterpret_cast<const u32x4*>(p);
  return __builtin_bit_cast(bf16x8, u);
}
__device__ __forceinline__ f32x4 zero4() {
  f32x4 v; v.x = 0.f; v.y = 0.f; v.z = 0.f; v.w = 0.f; return v;
}

// async global->LDS, 16B per lane; LDS dest = wave-uniform base + lane*16
#define ASYNC16(ldsp, gp)                                                      \
  __builtin_amdgcn_global_load_lds(                                            \
      (const __attribute__((address_space(1))) unsigned int*)(gp),             \
      (__attribute__((address_space(3))) unsigned int*)(ldsp), 16, 0, 0)

// ---------------------------------------------------------------------------
// prep (x8 vectorized): out[(b*L+l)*256+d] = bf16(a[(l*8+b)*256+d] (+badd))
// ---------------------------------------------------------------------------
__global__ void prep_add_kernel(const float* __restrict__ a,
                                const float* __restrict__ badd,
                                unsigned short* __restrict__ out,
                                int L, int n8) {
  int i = blockIdx.x * blockDim.x + threadIdx.x;
  if (i >= n8) return;
  int base = i * 8;
  int d = base & 255;
  int rest = base >> 8;
  int bb = rest & 7, l = rest >> 3;
  f32x4 x0 = *reinterpret_cast<const f32x4*>(a + base);
  f32x4 x1 = *reinterpret_cast<const f32x4*>(a + base + 4);
  if (badd) {
    f32x4 y0 = *reinterpret_cast<const f32x4*>(badd + base);
    f32x4 y1 = *reinterpret_cast<const f32x4*>(badd + base + 4);
    x0 += y0; x1 += y1;
  }
  u32x4 o;
  o.x = pack2(x0.x, x0.y); o.y = pack2(x0.z, x0.w);
  o.z = pack2(x1.x, x1.y); o.w = pack2(x1.z, x1.w);
  *reinterpret_cast<u32x4*>(out + (((size_t)bb * L + l) << 8) + d) = o;
}

// fused K/V prep: reads memory once (+pos), writes A_k (=mem+pos) and A_v (=mem)
__global__ void prep_kv_kernel(const float* __restrict__ mem,
                               const float* __restrict__ pos,
                               unsigned short* __restrict__ outK,
                               unsigned short* __restrict__ outV,
                               int n8) {
  int i = blockIdx.x * blockDim.x + threadIdx.x;
  if (i >= n8) return;
  int base = i * 8;
  int d = base & 255;
  int rest = base >> 8;
  int bb = rest & 7, l = rest >> 3;
  f32x4 m0 = *reinterpret_cast<const f32x4*>(mem + base);
  f32x4 m1 = *reinterpret_cast<const f32x4*>(mem + base + 4);
  f32x4 p0 = *reinterpret_cast<const f32x4*>(pos + base);
  f32x4 p1 = *reinterpret_cast<const f32x4*>(pos + base + 4);
  size_t oidx = (((size_t)bb * LK + l) << 8) + d;
  u32x4 ov;
  ov.x = pack2(m0.x, m0.y); ov.y = pack2(m0.z, m0.w);
  ov.z = pack2(m1.x, m1.y); ov.w = pack2(m1.z, m1.w);
  *reinterpret_cast<u32x4*>(outV + oidx) = ov;
  f32x4 k0 = m0 + p0, k1 = m1 + p1;
  u32x4 ok;
  ok.x = pack2(k0.x, k0.y); ok.y = pack2(k0.z, k0.w);
  ok.z = pack2(k1.x, k1.y); ok.w = pack2(k1.z, k1.w);
  *reinterpret_cast<u32x4*>(outK + oidx) = ok;
}

// fused 4-way f32->bf16 weight conversion; blockIdx.y selects tensor
__global__ void conv4_bf16_kernel(const float* __restrict__ s0, const float* __restrict__ s1,
                                  const float* __restrict__ s2, const float* __restrict__ s3,
                                  unsigned short* __restrict__ d0, unsigned short* __restrict__ d1,
                                  unsigned short* __restrict__ d2, unsigned short* __restrict__ d3,
                                  int n8) {
  int i = blockIdx.x * blockDim.x + threadIdx.x;
  if (i >= n8) return;
  const float* src; unsigned short* dst;
  switch (blockIdx.y) {
    case 0: src = s0; dst = d0; break;
    case 1: src = s1; dst = d1; break;
    case 2: src = s2; dst = d2; break;
    default: src = s3; dst = d3; break;
  }
  int base = i * 8;
  f32x4 x0 = *reinterpret_cast<const f32x4*>(src + base);
  f32x4 x1 = *reinterpret_cast<const f32x4*>(src + base + 4);
  u32x4 o;
  o.x = pack2(x0.x, x0.y); o.y = pack2(x0.z, x0.w);
  o.z = pack2(x1.x, x1.y); o.w = pack2(x1.z, x1.w);
  *reinterpret_cast<u32x4*>(dst + base) = o;
}

// ---------------------------------------------------------------------------
// W transpose (x2 fused): in f32 [1024 he][256 d] -> out bf16 [256 d][1024 he]
// grid (16,4,2): he0 = bx*64, d0 = by*64; z selects (Wq,WqT)/(Wk,WkT).
// ---------------------------------------------------------------------------
__global__ void __launch_bounds__(256)
transpose_w2_kernel(const float* __restrict__ inA, unsigned short* __restrict__ outA,
                    const float* __restrict__ inB, unsigned short* __restrict__ outB) {
  __shared__ float ts[64][65];
  const float* in = blockIdx.z ? inB : inA;
  unsigned short* out = blockIdx.z ? outB : outA;
  const int t = threadIdx.x;
  const int he0 = blockIdx.x * 64, d0 = blockIdx.y * 64;
  const int rh = t >> 6, c = t & 63;
#pragma unroll
  for (int i = 0; i < 16; ++i) {
    int r = i * 4 + rh;
    ts[r][c] = in[(size_t)(he0 + r) * 256 + d0 + c];
  }
  __syncthreads();
#pragma unroll
  for (int i = 0; i < 16; ++i) {
    int r = i * 4 + rh;  // d-local
    out[(size_t)(d0 + r) * 1024 + he0 + c] = f2bf(ts[c][r]);
  }
}

// ---------------------------------------------------------------------------
// NT GEMM (unchanged): global_load_lds(16B), XOR-swizzled LDS.
// C[m][n] = alpha * sum_k A[m][k]*B[n][k]
// ---------------------------------------------------------------------------
template <int OUT_MODE>
__global__ void __launch_bounds__(256)
gemm_nt_kernel(const unsigned short* __restrict__ A, int lda, long long sA,
               const unsigned short* __restrict__ B, int ldb, long long sB,
               void* __restrict__ Cv, int ldc, long long sC,
               int K, float alpha) {
  __shared__ __align__(16) unsigned short As[128 * 64];
  __shared__ __align__(16) unsigned short Bs[128 * 64];
  const int t = threadIdx.x;
  const int bm0 = blockIdx.y * 128;
  const int bn0 = blockIdx.x * 128;
  A += (size_t)blockIdx.z * sA + (size_t)bm0 * lda;
  B += (size_t)blockIdx.z * sB + (size_t)bn0 * ldb;
  const int lane = t & 63, w = t >> 6;
  const int wm = (w >> 1) * 64, wn = (w & 1) * 64;
  const int lr = lane & 15, quad = lane >> 4;
  const int srl = lane >> 3;
  const int sc = (lane & 7) ^ (srl & 7);

  f32x4 acc[4][4];
#pragma unroll
  for (int i = 0; i < 4; ++i)
#pragma unroll
    for (int j = 0; j < 4; ++j) acc[i][j] = zero4();

  for (int k0 = 0; k0 < K; k0 += 64) {
#pragma unroll
    for (int i = 0; i < 4; ++i) {
      int r0 = w * 32 + i * 8;
      ASYNC16(&As[r0 * 64], &A[(size_t)(r0 + srl) * lda + k0 + sc * 8]);
      ASYNC16(&Bs[r0 * 64], &B[(size_t)(r0 + srl) * ldb + k0 + sc * 8]);
    }
    __syncthreads();
#pragma unroll
    for (int ks = 0; ks < 2; ++ks) {
      bf16x8 af[4], bfv[4];
#pragma unroll
      for (int i = 0; i < 4; ++i) {
        int m = wm + i * 16 + lr;
        int pc = (ks * 4 + quad) ^ (lr & 7);
        af[i] = ld_bf8(&As[m * 64 + pc * 8]);
      }
#pragma unroll
      for (int j = 0; j < 4; ++j) {
        int n = wn + j * 16 + lr;
        int pc = (ks * 4 + quad) ^ (lr & 7);
        bfv[j] = ld_bf8(&Bs[n * 64 + pc * 8]);
      }
#pragma unroll
      for (int i = 0; i < 4; ++i)
#pragma unroll
        for (int j = 0; j < 4; ++j)
          acc[i][j] = __builtin_amdgcn_mfma_f32_16x16x32_bf16(af[i], bfv[j], acc[i][j], 0, 0, 0);
    }
    __syncthreads();
  }

  if (OUT_MODE == 0) {
    float* C = (float*)Cv + (size_t)blockIdx.z * sC;
#pragma unroll
    for (int i = 0; i < 4; ++i) {
      int m0 = bm0 + wm + i * 16 + quad * 4;
#pragma unroll
      for (int j = 0; j < 4; ++j) {
        int n = bn0 + wn + j * 16 + lr;
#pragma unroll
        for (int r = 0; r < 4; ++r)
          C[(size_t)(m0 + r) * ldc + n] = acc[i][j][r] * alpha;
      }
    }
  } else if (OUT_MODE == 1) {
    unsigned short* C = (unsigned short*)Cv + (size_t)blockIdx.z * sC;
#pragma unroll
    for (int i = 0; i < 4; ++i) {
      int m0 = bm0 + wm + i * 16 + quad * 4;
#pragma unroll
      for (int j = 0; j < 4; ++j) {
        int n = bn0 + wn + j * 16 + lr;
#pragma unroll
        for (int r = 0; r < 4; ++r)
          C[(size_t)(m0 + r) * ldc + n] = f2bf(acc[i][j][r] * alpha);
      }
    }
  } else {
    unsigned short* C = (unsigned short*)Cv;
#pragma unroll
    for (int i = 0; i < 4; ++i) {
      int m0 = bm0 + wm + i * 16 + quad * 4;
      int bb = m0 >> 12;
      int kp = m0 & 4095;
#pragma unroll
      for (int j = 0; j < 4; ++j) {
        int n = bn0 + wn + j * 16 + lr;
        s16x4 pk;
#pragma unroll
        for (int r = 0; r < 4; ++r) pk[r] = (short)f2bf(acc[i][j][r] * alpha);
        *reinterpret_cast<s16x4*>(&C[((size_t)(bb * 1024 + n)) * 4096 + kp]) = pk;
      }
    }
  }
}

// ---------------------------------------------------------------------------
// Flash attention (round-1 config, measured 189-202us — DO NOT regraft):
//   - single barrier per k-tile; prefetch of tile t+1 issued at tile top so the
//     whole tile's compute covers load latency before the barrier's vmcnt(0).
//   - NO XCD-grouping: R2/R3 showed grouping cuts FETCH 300->86MB but SLOWS the
//     kernel (202->247/302us): latency-bound; dispersed sharers are served by
//     L3 (K/V=128MB fits 256MB L3) with decorrelated misses.
//   - NO setprio (confounded regression R3; m190 neutral/negative on lockstep).
//   - V-swizzle key (row>>1)&3 (64B rows): conflicts 2.1e7 -> 1.26e7 (R1).
// grid (16=qt*2+ks, H, B), 256 thr = 4 waves; wave owns 32 q rows.
// ---------------------------------------------------------------------------
__global__ void __launch_bounds__(256, 2)
attn_kernel(const unsigned short* __restrict__ Qg,
            const unsigned short* __restrict__ Kg,
            const unsigned short* __restrict__ VTg,
            unsigned short* __restrict__ Opart,
            float* __restrict__ lpart) {
  __shared__ __align__(16) unsigned short Kt[2][32 * 256];  // [kpos][d], chunk^ (row&7)
  __shared__ __align__(16) unsigned short Vt[2][256 * 32];  // [e][kpos], chunk^ ((row>>1)&3)
  const int t = threadIdx.x;
  const int qt = blockIdx.x >> 1, ks = blockIdx.x & 1;
  const int h = blockIdx.y, b = blockIdx.z;
  const int lane = t & 63, w = t >> 6;
  const int lr = lane & 15, quad = lane >> 4;

  // Q B-frags: qf[nt][s]: q = qt*128+w*32+nt*16+lr, d = s*32 + quad*8..+7
  const unsigned short* Qrow0 =
      Qg + ((size_t)(b * 1024 + qt * 128 + w * 32 + lr)) * 1024 + h * 256;
  bf16x8 qf[2][8];
#pragma unroll
  for (int s = 0; s < 8; ++s) {
    qf[0][s] = ld_bf8(&Qrow0[s * 32 + quad * 8]);
    qf[1][s] = ld_bf8(&Qrow0[16 * 1024 + s * 32 + quad * 8]);
  }

  f32x4 Oacc[16][2];
#pragma unroll
  for (int m2 = 0; m2 < 16; ++m2) {
    Oacc[m2][0] = zero4();
    Oacc[m2][1] = zero4();
  }
  float lsum_r[2] = {0.f, 0.f};

  const unsigned short* Kb =
      Kg + ((size_t)(b * 4096 + ks * 2048)) * 1024 + h * 256;
  const unsigned short* Vb =
      VTg + ((size_t)(b * 1024 + h * 256)) * 4096 + ks * 2048;

  // staging index precompute
  const int k_rsub = lane >> 5;                 // row within pair
  const int k_chunk = lane & 31;                // phys chunk (of 32)
  const int v_rsub = lane >> 2;                 // row within 16
  const int v_chunk = lane & 3;                 // phys chunk (of 4)

#define ISSUE_TILE(kt, bufsel)                                                 \
  {                                                                            \
    _Pragma("unroll") for (int i = 0; i < 4; ++i) {                            \
      int r0 = w * 8 + i * 2;                                                  \
      int krow = r0 + k_rsub;                                                  \
      int kc = k_chunk ^ (krow & 7);                                           \
      ASYNC16(&Kt[bufsel][r0 * 256], &Kb[(size_t)((kt) + krow) * 1024 + kc * 8]); \
      int vr0 = (w * 4 + i) * 16;                                              \
      int ve = vr0 + v_rsub;                                                   \
      int vc = v_chunk ^ ((ve >> 1) & 3);                                      \
      ASYNC16(&Vt[bufsel][vr0 * 32], &Vb[(size_t)ve * 4096 + (kt) + vc * 8]);  \
    }                                                                          \
  }

  ISSUE_TILE(0, 0)
  __syncthreads();

  const int bpermA = (((quad & 1) * 32) + lr) * 4;  // src lane qs0*16+lr, bytes
  const int bpermB = bpermA + 64;                   // qs0+1

  for (int kt = 0; kt < 2048; kt += 32) {
    const int pbuf = (kt >> 5) & 1;
    // prefetch next tile into the other buffer (tail prefetch reads junk into
    // a never-read buffer; addresses stay inside the workspace)
    ISSUE_TILE(kt + 32, pbuf ^ 1)

    const unsigned short* Ktp = Kt[pbuf];
    const unsigned short* Vtp = Vt[pbuf];

    // S^T[kpos][q]: A = K (m=kpos), B = Q regs. 2 m-tiles x 2 n-tiles, ILP 4.
    f32x4 S[2][2];
    S[0][0] = zero4(); S[0][1] = zero4();
    S[1][0] = zero4(); S[1][1] = zero4();
#pragma unroll
    for (int s = 0; s < 8; ++s) {
      int pc = ((s * 4 + quad) ^ (lr & 7)) * 8;
      bf16x8 kf0 = ld_bf8(&Ktp[lr * 256 + pc]);
      bf16x8 kf1 = ld_bf8(&Ktp[(16 + lr) * 256 + pc]);
      S[0][0] = __builtin_amdgcn_mfma_f32_16x16x32_bf16(kf0, qf[0][s], S[0][0], 0, 0, 0);
      S[0][1] = __builtin_amdgcn_mfma_f32_16x16x32_bf16(kf0, qf[1][s], S[0][1], 0, 0, 0);
      S[1][0] = __builtin_amdgcn_mfma_f32_16x16x32_bf16(kf1, qf[0][s], S[1][0], 0, 0, 0);
      S[1][1] = __builtin_amdgcn_mfma_f32_16x16x32_bf16(kf1, qf[1][s], S[1][1], 0, 0, 0);
    }

    // exp + pack to bf16 pairs
    unsigned pk[2][2][2];
#pragma unroll
    for (int mt = 0; mt < 2; ++mt)
#pragma unroll
      for (int nt = 0; nt < 2; ++nt) {
        float p0 = __expf(S[mt][nt][0]);
        float p1 = __expf(S[mt][nt][1]);
        float p2 = __expf(S[mt][nt][2]);
        float p3 = __expf(S[mt][nt][3]);
        lsum_r[nt] += (p0 + p1) + (p2 + p3);
        pk[mt][nt][0] = pack2(p0, p1);
        pk[mt][nt][1] = pack2(p2, p3);
      }

    // P^T C-layout -> B-operand A..: dest lane (lr,quad) elem j needs
    // kpos=quad*8+j, q=nt*16+lr  => src tile mt=quad>>1, src quad
    // (quad&1)*2+(j>>2), reg j&3.  ds_bpermute both tiles + select.
    bf16x8 pfrag[2];
#pragma unroll
    for (int nt = 0; nt < 2; ++nt) {
      u32x4 bfw;
#pragma unroll
      for (int w2 = 0; w2 < 2; ++w2) {
        int f0 = __builtin_amdgcn_ds_bpermute(bpermA, (int)pk[0][nt][w2]);
        int f1 = __builtin_amdgcn_ds_bpermute(bpermA, (int)pk[1][nt][w2]);
        bfw[w2] = (unsigned)(quad < 2 ? f0 : f1);
        int g0 = __builtin_amdgcn_ds_bpermute(bpermB, (int)pk[0][nt][w2]);
        int g1 = __builtin_amdgcn_ds_bpermute(bpermB, (int)pk[1][nt][w2]);
        bfw[2 + w2] = (unsigned)(quad < 2 ? g0 : g1);
      }
      pfrag[nt] = __builtin_bit_cast(bf16x8, bfw);
    }

    // PV: O^T[e][q] += V^T * P^T ; A = V^T (m=e), k = 32 kpos, 1 k-step
#pragma unroll
    for (int m2 = 0; m2 < 16; ++m2) {
      bf16x8 vf = ld_bf8(&Vtp[(m2 * 16 + lr) * 32 + (quad ^ ((lr >> 1) & 3)) * 8]);
      Oacc[m2][0] = __builtin_amdgcn_mfma_f32_16x16x32_bf16(vf, pfrag[0], Oacc[m2][0], 0, 0, 0);
      Oacc[m2][1] = __builtin_amdgcn_mfma_f32_16x16x32_bf16(vf, pfrag[1], Oacc[m2][1], 0, 0, 0);
    }
    __syncthreads();
  }
#undef ISSUE_TILE

  const int pidx = b * 4 + h;
  // lsum: reduce across quads (q lives in lr; partials spread over quad)
#pragma unroll
  for (int nt = 0; nt < 2; ++nt) {
    float l = lsum_r[nt];
    l += __shfl_xor(l, 16, 64);
    l += __shfl_xor(l, 32, 64);
    if (quad == 0)
      lpart[((size_t)(ks * 32 + pidx)) * 1024 + qt * 128 + w * 32 + nt * 16 + lr] = l;
  }

  // Opart[ks][p][e][q] bf16 (same format as combine expects)
  const size_t base = ((size_t)(ks * 32 + pidx)) * 256 * 1024;
  const int qg0 = qt * 128 + w * 32 + lr;
#pragma unroll
  for (int m2 = 0; m2 < 16; ++m2) {
#pragma unroll
    for (int nt = 0; nt < 2; ++nt) {
#pragma unroll
      for (int r = 0; r < 4; ++r) {
        int e = m2 * 16 + quad * 4 + r;
        Opart[base + (size_t)e * 1024 + qg0 + nt * 16] = f2bf(Oacc[m2][nt][r]);
      }
    }
  }
}

// ---------------------------------------------------------------------------
// combine: O = (Oa+Ob)/(la+lb), transpose [e][q] -> row-major [q][h*256+e]
// ---------------------------------------------------------------------------
__global__ void __launch_bounds__(256)
combine_kernel(const unsigned short* __restrict__ Opart,
               const float* __restrict__ lpart,
               unsigned short* __restrict__ Oall) {
  __shared__ float rl[64];
  __shared__ __align__(16) unsigned short T[64][264];
  const int t = threadIdx.x;
  const int qt = blockIdx.x, h = blockIdx.y, b = blockIdx.z;
  const int p = b * 4 + h;
  const int q0 = qt * 64;
  const size_t slabO = (size_t)32 * 256 * 1024;
  const size_t slabL = (size_t)32 * 1024;
  if (t < 64) {
    float la = lpart[(size_t)p * 1024 + q0 + t];
    float lb = lpart[slabL + (size_t)p * 1024 + q0 + t];
    rl[t] = 1.f / (la + lb);
  }
  __syncthreads();
  const int er = t >> 3, q8 = t & 7;
#pragma unroll
  for (int ei = 0; ei < 8; ++ei) {
    int e = ei * 32 + er;
    size_t idx = ((size_t)p * 256 + e) * 1024 + q0 + q8 * 8;
    u32x4 ua = *reinterpret_cast<const u32x4*>(&Opart[idx]);
    u32x4 ub = *reinterpret_cast<const u32x4*>(&Opart[slabO + idx]);
#pragma unroll
    for (int wd = 0; wd < 4; ++wd) {
      unsigned a = ((const unsigned*)&ua)[wd], bb2 = ((const unsigned*)&ub)[wd];
      float a0 = __builtin_bit_cast(float, a << 16);
      float a1 = __builtin_bit_cast(float, a & 0xFFFF0000u);
      float b0 = __builtin_bit_cast(float, bb2 << 16);
      float b1 = __builtin_bit_cast(float, bb2 & 0xFFFF0000u);
      int qA = q8 * 8 + wd * 2;
      T[qA + 0][e] = f2bf((a0 + b0) * rl[qA + 0]);
      T[qA + 1][e] = f2bf((a1 + b1) * rl[qA + 1]);
    }
  }
  __syncthreads();
  const int ql = t >> 2, ec = t & 3;
  const size_t orow = ((size_t)(b * 1024 + q0 + ql)) * 1024 + h * 256;
#pragma unroll
  for (int i = 0; i < 8; ++i) {
    int ch = ec * 8 + i;
    *reinterpret_cast<u32x4*>(&Oall[orow + ch * 8]) =
        *reinterpret_cast<const u32x4*>(&T[ql][ch * 8]);
  }
}

// ---------------------------------------------------------------------------
// residual + LayerNorm: one wave per row of 256
// ---------------------------------------------------------------------------
__global__ void __launch_bounds__(256)
fc_ln_kernel(const float* __restrict__ fc, const float* __restrict__ tgt,
             const float* __restrict__ g, const float* __restrict__ bb,
             float* __restrict__ y) {
  int row = blockIdx.x * 4 + (threadIdx.x >> 6);
  int lane = threadIdx.x & 63;
  int b = row >> 10, q = row & 1023;
  const float* fr = fc + (size_t)row * 256;
  const float* tr = tgt + ((size_t)(q * 8 + b)) * 256;
  float x[4];
  float s = 0.f, ss = 0.f;
#pragma unroll
  for (int e = 0; e < 4; ++e) {
    x[e] = fr[lane + e * 64] + tr[lane + e * 64];
    s += x[e];
    ss += x[e] * x[e];
  }
#pragma unroll
  for (int d = 1; d < 64; d <<= 1) {
    s += __shfl_xor(s, d, 64);
    ss += __shfl_xor(ss, d, 64);
  }
  float mu = s * (1.f / 256.f);
  float var = ss * (1.f / 256.f) - mu * mu;
  float rs = rsqrtf(var + 1e-5f);
  float* yr = y + ((size_t)(q * 8 + b)) * 256;
#pragma unroll
  for (int e = 0; e < 4; ++e)
    yr[lane + e * 64] = (x[e] - mu) * rs * g[lane + e * 64] + bb[lane + e * 64];
}

// ---------------------------------------------------------------------------
// Workspace lifetime map (launch-ordered; ws >= 182MB proven by rounds 0-7).
//   L1    transpose x2   -> WqT[38,38.5) WkT[38.5,39)
//   L2    GT gemm        -> GT [39,39.125)          (reads WqT/WkT)
//   L3    prep A_q       -> A_q[2,6)
//   L4    prep_kv        -> A_k[6,22) A_v[22,38)
//   L5    Tq gemm        -> Tq [40,44)              (reads A_q, GT; in Qall rgn)
//   L6    logits gemm    -> attn_mean (d_out)       (reads Tq, A_k)
//   L7    conv4          -> W*_b [0,2)
//   L8    Qall gemm      -> [38,54)                 (kills WqT/WkT/GT/Tq: dead)
//   L9    Kall gemm      -> [54,118)
//   L10   VTb gemm       -> [118,182)               (kills A_v: last read)
//   L11   attn           -> Opart[2,34) lpart[36,36.25)
//   L12   combine        -> Oall[118,134)           (VTb dead)
//   L13   fc gemm        -> fcout[140,148);  L14 ln -> y (d_out)
// R8 change: prep_kv writes A_v EARLY (L4), so Tq moved out of A_v's region
// to [40,44) inside Qall (written L5, read L6, dead before Qall gemm L8).
// ---------------------------------------------------------------------------
extern "C" void kernel_launch(void* const* d_in, const int* in_sizes, int n_in,
                              void* d_out, int out_size, void* d_ws, size_t ws_size,
                              hipStream_t stream) {
  (void)in_sizes; (void)n_in; (void)out_size; (void)ws_size;
  const float* tgt    = (const float*)d_in[0];
  const float* memory = (const float*)d_in[1];
  const float* pos    = (const float*)d_in[2];
  const float* qpos   = (const float*)d_in[3];
  const float* Wq     = (const float*)d_in[4];
  const float* Wk     = (const float*)d_in[5];
  const float* Wv     = (const float*)d_in[6];
  const float* Wfc    = (const float*)d_in[7];
  const float* lng    = (const float*)d_in[8];
  const float* lnb    = (const float*)d_in[9];
  float* out = (float*)d_out;

  char* ws = (char*)d_ws;
  const size_t MB = 1024 * 1024;
  unsigned short* Wq_b  = (unsigned short*)(ws + 0);
  unsigned short* Wk_b  = (unsigned short*)(ws + 512 * 1024);
  unsigned short* Wv_b  = (unsigned short*)(ws + 1 * MB);
  unsigned short* Wfc_b = (unsigned short*)(ws + 1 * MB + 512 * 1024);
  unsigned short* A_q   = (unsigned short*)(ws + 2 * MB);
  unsigned short* A_k   = (unsigned short*)(ws + 6 * MB);
  unsigned short* A_v   = (unsigned short*)(ws + 22 * MB);
  unsigned short* Qall  = (unsigned short*)(ws + 38 * MB);
  unsigned short* WqT   = (unsigned short*)(ws + 38 * MB);                 // [38,38.5) before Qall
  unsigned short* WkT   = (unsigned short*)(ws + 38 * MB + 512 * 1024);    // [38.5,39)
  unsigned short* GT    = (unsigned short*)(ws + 39 * MB);                 // [39,39.125)
  unsigned short* Tq    = (unsigned short*)(ws + 40 * MB);                 // [40,44) before Qall
  unsigned short* Kall  = (unsigned short*)(ws + 54 * MB);
  unsigned short* VTb   = (unsigned short*)(ws + 118 * MB);
  unsigned short* Opart = (unsigned short*)(ws + 2 * MB);
  float* lpart          = (float*)(ws + 36 * MB);
  unsigned short* Oall  = (unsigned short*)(ws + 118 * MB);
  float* fcout          = (float*)(ws + 140 * MB);
  float* y = out;
  float* attn_mean = out + (size_t)LQ * NBATCH * DM;

  int n_q = LQ * NBATCH * DM;
  int n_k = LK * NBATCH * DM;
  int n_w8 = 1024 * 256 / 8;

  // --- factorized attn_mean path first (temps die before Qall/A_v writes) ---
  transpose_w2_kernel<<<dim3(16, 4, 2), 256, 0, stream>>>(Wq, WqT, Wk, WkT);
  // GT[d'][d] = (scale/H) * sum_he Wk[he][d'] * Wq[he][d]   (256x256, K=1024)
  gemm_nt_kernel<1><<<dim3(2, 2, 1), 256, 0, stream>>>(
      WkT, 1024, 0LL, WqT, 1024, 0LL, (void*)GT, 256, 0LL, 1024, 0.015625f);
  prep_add_kernel<<<(n_q / 8 + 255) / 256, 256, 0, stream>>>(tgt, qpos, A_q, LQ, n_q / 8);
  prep_kv_kernel<<<(n_k / 8 + 255) / 256, 256, 0, stream>>>(memory, pos, A_k, A_v, n_k / 8);
  // Tq[bq][d'] = sum_d A_q[bq][d] * GT[d'][d]   (8192x256, K=256)
  gemm_nt_kernel<1><<<dim3(2, 64, 1), 256, 0, stream>>>(
      A_q, 256, 0LL, GT, 256, 0LL, (void*)Tq, 256, 0LL, 256, 1.0f);
  // attn_mean[b][q][k'] = sum_d' Tq[bq][d'] * A_k[bk'][d']  (K=256, was K=1024)
  gemm_nt_kernel<0><<<dim3(32, 8, 8), 256, 0, stream>>>(
      Tq, 256, (long long)(1024 * 256), A_k, 256, (long long)(4096 * 256),
      (void*)attn_mean, 4096, (long long)4096 * 1024, 256, 1.0f);

  // --- main path ---
  conv4_bf16_kernel<<<dim3((n_w8 + 255) / 256, 4), 256, 0, stream>>>(
      Wq, Wk, Wv, Wfc, Wq_b, Wk_b, Wv_b, Wfc_b, n_w8);

  gemm_nt_kernel<1><<<dim3(8, 64, 1), 256, 0, stream>>>(
      A_q, 256, 0LL, Wq_b, 256, 0LL, (void*)Qall, 1024, 0LL, 256, 0.0625f);
  gemm_nt_kernel<1><<<dim3(8, 256, 1), 256, 0, stream>>>(
      A_k, 256, 0LL, Wk_b, 256, 0LL, (void*)Kall, 1024, 0LL, 256, 1.0f);
  gemm_nt_kernel<2><<<dim3(8, 256, 1), 256, 0, stream>>>(
      A_v, 256, 0LL, Wv_b, 256, 0LL, (void*)VTb, 0, 0LL, 256, 1.0f);

  attn_kernel<<<dim3(16, NH, NBATCH), 256, 0, stream>>>(Qall, Kall, VTb, Opart, lpart);
  combine_kernel<<<dim3(16, NH, NBATCH), 256, 0, stream>>>(Opart, lpart, Oall);
  gemm_nt_kernel<0><<<dim3(2, 64, 1), 256, 0, stream>>>(
      Oall, 1024, 0LL, Wfc_b, 1024, 0LL, (void*)fcout, 256, 0LL, 1024, 1.0f);
  fc_ln_kernel<<<2048, 256, 0, stream>>>(fcout, tgt, lng, lnb, y);
}